// Round 8
// baseline (875.468 us; speedup 1.0000x reference)
//
#include <hip/hip_runtime.h>
#include <math.h>

#define BIMG 8
#define HW 9216
#define CENC 512
#define NN 128
#define DD 256
#define NHEAD 8
#define DH 32
#define ROWS1 1024
#define ROWS2 2048
#define NBLK 512

typedef unsigned long long ull;
typedef unsigned short u16;
typedef __attribute__((ext_vector_type(4))) float f32x4;
typedef __attribute__((ext_vector_type(4))) unsigned u32x4;
typedef __attribute__((ext_vector_type(2))) unsigned u32x2;

__device__ __forceinline__ u16 f2bf(float f) {
  unsigned u = __float_as_uint(f);
  u += 0x7fffu + ((u >> 16) & 1u);
  return (u16)(u >> 16);
}
__device__ __forceinline__ float bf2f(unsigned h) { return __uint_as_float(h << 16); }
__device__ __forceinline__ unsigned pack2(float a, float b) {
  return (unsigned)f2bf(a) | ((unsigned)f2bf(b) << 16);
}
__device__ __forceinline__ void mfma_b(f32x4& acc, u32x4 a, u32x4 b) {
  asm volatile("v_mfma_f32_16x16x32_bf16 %0, %1, %2, %0" : "+v"(acc) : "v"(a), "v"(b));
}

__device__ __forceinline__ ull cmpex_keep(ull k, ull o, bool keepMax) {
  return ((k > o) == keepMax) ? k : o;
}
__device__ __forceinline__ void bsort64(ull& k, int lane) {
#pragma unroll
  for (int size = 2; size <= 64; size <<= 1) {
#pragma unroll
    for (int stride = size >> 1; stride > 0; stride >>= 1) {
      ull o = __shfl_xor(k, stride);
      bool keepMax = (((lane & size) == 0) == ((lane & stride) == 0));
      k = cmpex_keep(k, o, keepMax);
    }
  }
}
__device__ __forceinline__ void bmerge64(ull& top, ull b, int lane) {
  ull rev = __shfl_xor(b, 63);
  ull m = top > rev ? top : rev;
#pragma unroll
  for (int stride = 32; stride > 0; stride >>= 1) {
    ull o = __shfl_xor(m, stride);
    m = cmpex_keep(m, o, (lane & stride) == 0);
  }
  top = m;
}

// ---- launch 1: 0..31 top-64 ; 32..799 weight transpose ; 800..831 cls_W1 -> bf16 ----
__global__ __launch_bounds__(256) void head_kernel(const float* __restrict__ score_s,
                                                   const float* __restrict__ score_t,
                                                   int* __restrict__ idx_out,
                                                   float* __restrict__ loss_acc,
                                                   const float* __restrict__ hw1,
                                                   const float* __restrict__ hw2,
                                                   const float* __restrict__ iw,
                                                   const float* __restrict__ cw,
                                                   const float* __restrict__ aw,
                                                   const float* __restrict__ clsW1,
                                                   u16* __restrict__ wt,
                                                   u16* __restrict__ w1t) {
  __shared__ ull sm[256];
  __shared__ float tile[32][33];
  int tid = threadIdx.x;
  if (blockIdx.x < 32) {
    int blk = blockIdx.x;
    int bi = blk >> 1, neg = blk & 1;
    int lane = tid & 63, w = tid >> 6;
    if (blk == 0 && tid < 32) ((unsigned*)loss_acc)[tid] = 0u;  // losses, ticket, barrier ctrs
    const float* sp = (bi < 8 ? score_s : score_t) + (size_t)(bi & 7) * HW;
    int q0 = w * 36;
    ull keys[36];
#pragma unroll
    for (int j = 0; j < 36; ++j) {
      float x = sp[(q0 + j) * 64 + lane];
      unsigned ub = __float_as_uint(x);
      unsigned u = (ub & 0x80000000u) ? ~ub : (ub | 0x80000000u);
      if (neg) u = ~u;
      int gi = (q0 + j) * 64 + lane;
      keys[j] = ((ull)u << 32) | (unsigned)(~gi);
    }
    ull top1 = keys[0];  bsort64(top1, lane);
    ull top2 = keys[18]; bsort64(top2, lane);
#pragma unroll
    for (int j = 1; j < 18; ++j) {
      ull k1 = keys[j], k2 = keys[18 + j];
      bsort64(k1, lane);
      bsort64(k2, lane);
      bmerge64(top1, k1, lane);
      bmerge64(top2, k2, lane);
    }
    bmerge64(top1, top2, lane);
    sm[w * 64 + lane] = top1;
    __syncthreads();
    if (w < 2) {
      ull a = sm[(2 * w) * 64 + lane];
      ull b = sm[(2 * w + 1) * 64 + (63 - lane)];
      ull m = a > b ? a : b;
#pragma unroll
      for (int stride = 32; stride > 0; stride >>= 1) {
        ull o = __shfl_xor(m, stride);
        m = cmpex_keep(m, o, (lane & stride) == 0);
      }
      sm[(2 * w) * 64 + lane] = m;
    }
    __syncthreads();
    if (w == 0) {
      ull a = sm[lane];
      ull b = sm[128 + (63 - lane)];
      ull m = a > b ? a : b;
#pragma unroll
      for (int stride = 32; stride > 0; stride >>= 1) {
        ull o = __shfl_xor(m, stride);
        m = cmpex_keep(m, o, (lane & stride) == 0);
      }
      idx_out[bi * NN + neg * 64 + lane] = (int)(~(unsigned)(m & 0xffffffffull));
    }
  } else if (blockIdx.x < 800) {
    int bid = blockIdx.x - 32;
    const float* src; u16* dst; int K, k0, n0;
    if (bid < 128) {
      src = hw1; dst = wt; K = 512;
      k0 = (bid >> 3) * 32; n0 = (bid & 7) * 32;
    } else {
      int id2 = bid - 128;
      int m = id2 >> 6, tt = id2 & 63;
      K = 256;
      k0 = (tt >> 3) * 32; n0 = (tt & 7) * 32;
      src = (m == 0) ? hw2 : (m < 5) ? iw + (size_t)(m - 1) * 65536
          : (m < 9) ? cw + (size_t)(m - 5) * 65536 : aw;
      dst = wt + 131072 + (size_t)m * 65536;
    }
    int r = tid >> 3, c = (tid & 7) * 4;
    float4 v = *(const float4*)&src[(size_t)(k0 + r) * 256 + n0 + c];
    tile[r][c] = v.x; tile[r][c + 1] = v.y; tile[r][c + 2] = v.z; tile[r][c + 3] = v.w;
    __syncthreads();
    u32x2 o;
    o[0] = pack2(tile[c][r], tile[c + 1][r]);
    o[1] = pack2(tile[c + 2][r], tile[c + 3][r]);
    *(u32x2*)&dst[(size_t)(n0 + r) * K + k0 + c] = o;
  } else {
    int bid3 = blockIdx.x - 800;     // cls_W1 [256][128] -> bf16 [128][256]
    int k0 = (bid3 >> 2) * 32, n0 = (bid3 & 3) * 32;
    int r = tid >> 3, c = (tid & 7) * 4;
    float4 v = *(const float4*)&clsW1[(size_t)(k0 + r) * 128 + n0 + c];
    tile[r][c] = v.x; tile[r][c + 1] = v.y; tile[r][c + 2] = v.z; tile[r][c + 3] = v.w;
    __syncthreads();
    u32x2 o;
    o[0] = pack2(tile[c][r], tile[c + 1][r]);
    o[1] = pack2(tile[c + 2][r], tile[c + 3][r]);
    *(u32x2*)&w1t[(size_t)(n0 + r) * 256 + k0 + c] = o;
  }
}

// ---------------- grid barrier: 8 sub-counters + master flag ----------------
__device__ __forceinline__ void gbar(int* bars, int phase) {
  __syncthreads();
  if (threadIdx.x == 0) {
    int sub = blockIdx.x & 7;
    int v = __hip_atomic_fetch_add(&bars[sub], 1, __ATOMIC_RELEASE,
                                   __HIP_MEMORY_SCOPE_AGENT) + 1;
    if (v == (NBLK / 8) * phase)
      __hip_atomic_fetch_add(&bars[8], 1, __ATOMIC_RELEASE, __HIP_MEMORY_SCOPE_AGENT);
    while (__hip_atomic_load(&bars[8], __ATOMIC_RELAXED, __HIP_MEMORY_SCOPE_AGENT) < 8 * phase)
      __builtin_amdgcn_s_sleep(2);
  }
  __syncthreads();
  __threadfence();
}

__device__ __forceinline__ void ticket_finalize(float* acc, float* out) {
  __threadfence();
  int tk = atomicAdd((int*)acc + 3, 1);
  if (tk == NBLK - 1) {
    float a0 = atomicAdd(acc + 0, 0.0f);
    float a1 = atomicAdd(acc + 1, 0.0f);
    out[ROWS1 * DD] = a0 + 10.0f * a1;
  }
}

// ---------------- 16x64 MFMA GEMM tile, K chunked by 256, LNopt on A ----------------
__device__ void gemm16x64(const u16* __restrict__ A, const u16* __restrict__ Wt,
                          const float* __restrict__ bias, u16* Cb, float* Cf,
                          const float* sin, int relu, float* sout,
                          int m0, int n0, int K, char* smc) {
  u16 (*As)[264] = (u16(*)[264])smc;
  u16 (*Bs)[264] = (u16(*)[264])(smc + 16 * 264 * 2);
  float* mS = (float*)(smc + 80 * 264 * 2);
  float* rS = mS + 16;
  int t = threadIdx.x, l = t & 63, w = t >> 6;
  if (sin) {
    if (t < 16) {
      const float* sp = sin + (size_t)(m0 + t) * 32;
      float s = 0.f, q = 0.f;
#pragma unroll
      for (int i = 0; i < 16; ++i) { s += sp[i]; q += sp[16 + i]; }
      float mm = s * (1.f / 256.f);
      mS[t] = mm;
      rS[t] = rsqrtf(fmaxf(q * (1.f / 256.f) - mm * mm, 0.f) + 1e-5f);
    }
    __syncthreads();
  }
  f32x4 acc = {0.f, 0.f, 0.f, 0.f};
  for (int ch = 0; ch < K; ch += 256) {
#pragma unroll
    for (int i = 0; i < 2; ++i) {
      int e = t + i * 256;
      int row = e >> 5, c8 = (e & 31) * 8;
      u32x4 av = *(const u32x4*)&A[(size_t)(m0 + row) * K + ch + c8];
      if (sin) {
        float mm = mS[row], rr = rS[row];
#pragma unroll
        for (int j = 0; j < 4; ++j) {
          float f0 = (bf2f(av[j] & 0xffffu) - mm) * rr;
          float f1 = (bf2f(av[j] >> 16) - mm) * rr;
          if (relu) { f0 = fmaxf(f0, 0.f); f1 = fmaxf(f1, 0.f); }
          av[j] = pack2(f0, f1);
        }
      }
      *(u32x4*)&As[row][c8] = av;
    }
#pragma unroll
    for (int i = 0; i < 8; ++i) {
      int e = t + i * 256;
      int row = e >> 5, c8 = (e & 31) * 8;
      *(u32x4*)&Bs[row][c8] = *(const u32x4*)&Wt[(size_t)(n0 + row) * K + ch + c8];
    }
    __syncthreads();
    int fra = l & 15, frk = (l >> 4) * 8, fbn = w * 16 + (l & 15);
#pragma unroll
    for (int ks = 0; ks < 8; ++ks) {
      u32x4 af = *(const u32x4*)&As[fra][ks * 32 + frk];
      u32x4 bf = *(const u32x4*)&Bs[fbn][ks * 32 + frk];
      mfma_b(acc, af, bf);
    }
    __syncthreads();
  }
  asm volatile("s_nop 7\n\ts_nop 7" ::);
  int col0 = n0 + w * 16 + (l & 15);
  float bb = bias ? bias[col0] : 0.f;
  int slot = (n0 >> 4) + w;
#pragma unroll
  for (int r = 0; r < 4; ++r) {
    int row = m0 + (l >> 4) * 4 + r;
    float o = acc[r] + bb;
    if (Cb) Cb[(size_t)row * 256 + col0] = f2bf(o);
    if (Cf && row < ROWS1) Cf[(size_t)row * 256 + col0] = o;
    if (sout) {
      float s = o, q = o * o;
#pragma unroll
      for (int m = 1; m < 16; m <<= 1) { s += __shfl_xor(s, m); q += __shfl_xor(q, m); }
      if ((l & 15) == 0) {
        sout[(size_t)row * 32 + slot] = s;
        sout[(size_t)row * 32 + 16 + slot] = q;
      }
    }
  }
}

// ---------------- attention (64 q-rows per logical blk, 4 j-quarters) ----------------
__device__ void attn_dev(const u16* __restrict__ q, const u16* __restrict__ k,
                         const u16* __restrict__ v, u16* __restrict__ o,
                         int swap, int blk, char* smc) {
  float (*Ks)[DH] = (float(*)[DH])smc;
  float (*Vs)[DH] = (float(*)[DH])(smc + 16384);
  float (*Ex)[3][34] = (float(*)[3][34])(smc + 32768);
  int bb = blk >> 4, h = (blk >> 1) & 7, qh = blk & 1;
  int kb = swap ? (bb ^ 8) : bb;
  int t = threadIdx.x;
  int rr = t & 63, part = t >> 6;
  for (int e = t; e < 1024; e += 256) {
    int which = e >> 9;
    int idx2 = e & 511;
    int r = idx2 >> 2, c8 = (idx2 & 3) * 8;
    u32x4 val = *(const u32x4*)&(which ? v : k)[(size_t)(kb * NN + r) * DD + h * DH + c8];
    float* dst = which ? &Vs[r][c8] : &Ks[r][c8];
#pragma unroll
    for (int i = 0; i < 4; ++i) {
      dst[2 * i]     = bf2f(val[i] & 0xffffu);
      dst[2 * i + 1] = bf2f(val[i] >> 16);
    }
  }
  __syncthreads();
  int qrow = bb * NN + qh * 64 + rr;
  float4 q4[8];
  {
    const u16* qp = q + (size_t)qrow * DD + h * DH;
#pragma unroll
    for (int c4 = 0; c4 < 4; ++c4) {
      u32x4 u = *(const u32x4*)&qp[c4 * 8];
      q4[c4 * 2].x = bf2f(u[0] & 0xffffu); q4[c4 * 2].y = bf2f(u[0] >> 16);
      q4[c4 * 2].z = bf2f(u[1] & 0xffffu); q4[c4 * 2].w = bf2f(u[1] >> 16);
      q4[c4 * 2 + 1].x = bf2f(u[2] & 0xffffu); q4[c4 * 2 + 1].y = bf2f(u[2] >> 16);
      q4[c4 * 2 + 1].z = bf2f(u[3] & 0xffffu); q4[c4 * 2 + 1].w = bf2f(u[3] >> 16);
    }
  }
  const float scale = 0.17677669529663687f;
  int j0 = part * 32;
  float mx = -1e30f;
  for (int j = j0; j < j0 + 32; ++j) {
    const float4* kp = (const float4*)Ks[j];
    float s = 0.f;
#pragma unroll
    for (int c4 = 0; c4 < 8; ++c4) {
      float4 kv = kp[c4];
      s += q4[c4].x * kv.x + q4[c4].y * kv.y + q4[c4].z * kv.z + q4[c4].w * kv.w;
    }
    mx = fmaxf(mx, s * scale);
  }
  float acc[DH];
#pragma unroll
  for (int c = 0; c < DH; ++c) acc[c] = 0.f;
  float den = 0.f;
  for (int j = j0; j < j0 + 32; ++j) {
    const float4* kp = (const float4*)Ks[j];
    float s = 0.f;
#pragma unroll
    for (int c4 = 0; c4 < 8; ++c4) {
      float4 kv = kp[c4];
      s += q4[c4].x * kv.x + q4[c4].y * kv.y + q4[c4].z * kv.z + q4[c4].w * kv.w;
    }
    float e = __expf(s * scale - mx);
    den += e;
    const float4* vp = (const float4*)Vs[j];
#pragma unroll
    for (int c4 = 0; c4 < 8; ++c4) {
      float4 vv = vp[c4];
      acc[c4 * 4 + 0] += e * vv.x; acc[c4 * 4 + 1] += e * vv.y;
      acc[c4 * 4 + 2] += e * vv.z; acc[c4 * 4 + 3] += e * vv.w;
    }
  }
  if (part) {
#pragma unroll
    for (int c = 0; c < DH; ++c) Ex[rr][part - 1][c] = acc[c];
    Ex[rr][part - 1][32] = mx;
    Ex[rr][part - 1][33] = den;
  }
  __syncthreads();
  if (part == 0) {
    float M = mx;
#pragma unroll
    for (int p = 0; p < 3; ++p) M = fmaxf(M, Ex[rr][p][32]);
    float f0 = __expf(mx - M);
    float fp[3];
    float dt = den * f0;
#pragma unroll
    for (int p = 0; p < 3; ++p) { fp[p] = __expf(Ex[rr][p][32] - M); dt += Ex[rr][p][33] * fp[p]; }
    float inv = 1.0f / dt;
    unsigned ovu[16];
#pragma unroll
    for (int c = 0; c < 16; ++c) {
      float x0 = acc[2 * c] * f0, x1 = acc[2 * c + 1] * f0;
#pragma unroll
      for (int p = 0; p < 3; ++p) { x0 += Ex[rr][p][2 * c] * fp[p]; x1 += Ex[rr][p][2 * c + 1] * fp[p]; }
      ovu[c] = pack2(x0 * inv, x1 * inv);
    }
    unsigned* op = (unsigned*)(o + (size_t)qrow * DD + h * DH);
#pragma unroll
    for (int i = 0; i < 4; ++i) {
      u32x4 w4;
      w4[0] = ovu[4 * i]; w4[1] = ovu[4 * i + 1]; w4[2] = ovu[4 * i + 2]; w4[3] = ovu[4 * i + 3];
      *(u32x4*)&op[4 * i] = w4;
    }
  }
}

// ---------------- sinkhorn per image pair (256 threads) ----------------
__device__ void sinkhorn_dev(const u16* __restrict__ bufH, const u16* __restrict__ wt_af,
                             float* acc, float* out, int b, char* smc) {
  u16 (*tmpL)[264] = (u16(*)[264])smc;
  float (*Km)[133] = (float(*)[133])smc;
  float* u_ = (float*)(smc + 68096);
  float* v_ = u_ + 128;
  float* red = v_ + 128;
  int t = threadIdx.x, l = t & 63, w = t >> 6;
  const u16* c1 = bufH + (size_t)(b * 128) * 256;
  const u16* c2 = bufH + (size_t)(1024 + b * 128) * 256;
  // stage A: tmp = c1 @ aff  (wave w -> rows w*32..+31, all 256 cols in 2 halves)
  for (int ch = 0; ch < 2; ++ch) {
    f32x4 a2[2][8];
#pragma unroll
    for (int rt = 0; rt < 2; ++rt)
#pragma unroll
      for (int i = 0; i < 8; ++i) a2[rt][i] = (f32x4){0.f, 0.f, 0.f, 0.f};
#pragma unroll
    for (int ks = 0; ks < 8; ++ks) {
      int kk = ks * 32 + (l >> 4) * 8;
      u32x4 a0 = *(const u32x4*)&c1[(size_t)(w * 32 + (l & 15)) * 256 + kk];
      u32x4 a1 = *(const u32x4*)&c1[(size_t)(w * 32 + 16 + (l & 15)) * 256 + kk];
#pragma unroll
      for (int i = 0; i < 8; ++i) {
        u32x4 bf = *(const u32x4*)&wt_af[(size_t)(ch * 128 + i * 16 + (l & 15)) * 256 + kk];
        mfma_b(a2[0][i], a0, bf);
        mfma_b(a2[1][i], a1, bf);
      }
    }
    asm volatile("s_nop 7\n\ts_nop 7" ::);
#pragma unroll
    for (int rt = 0; rt < 2; ++rt)
#pragma unroll
      for (int i = 0; i < 8; ++i) {
        int col = ch * 128 + i * 16 + (l & 15);
        int rb = w * 32 + rt * 16 + (l >> 4) * 4;
#pragma unroll
        for (int r2 = 0; r2 < 4; ++r2)
          tmpL[rb + r2][col] = f2bf(a2[rt][i][r2]);
      }
  }
  __syncthreads();
  // stage B: Km = tmp @ c2^T (own rows; read before aliased overwrite)
  f32x4 aB[2][8];
#pragma unroll
  for (int rt = 0; rt < 2; ++rt)
#pragma unroll
    for (int i = 0; i < 8; ++i) aB[rt][i] = (f32x4){0.f, 0.f, 0.f, 0.f};
#pragma unroll
  for (int ks = 0; ks < 8; ++ks) {
    int kk = ks * 32 + (l >> 4) * 8;
    u32x4 a0 = *(const u32x4*)&tmpL[w * 32 + (l & 15)][kk];
    u32x4 a1 = *(const u32x4*)&tmpL[w * 32 + 16 + (l & 15)][kk];
#pragma unroll
    for (int i = 0; i < 8; ++i) {
      u32x4 bf = *(const u32x4*)&c2[(size_t)(i * 16 + (l & 15)) * 256 + kk];
      mfma_b(aB[0][i], a0, bf);
      mfma_b(aB[1][i], a1, bf);
    }
  }
  asm volatile("s_nop 7\n\ts_nop 7" ::);
  __syncthreads();
#pragma unroll
  for (int rt = 0; rt < 2; ++rt)
#pragma unroll
    for (int i = 0; i < 8; ++i) {
      int col = i * 16 + (l & 15);
      int rb = w * 32 + rt * 16 + (l >> 4) * 4;
#pragma unroll
      for (int r2 = 0; r2 < 4; ++r2)
        Km[rb + r2][col] = aB[rt][i][r2];
    }
  __syncthreads();
  // instance norm
  int r = t >> 1, hf = t & 1, cb = hf * 64;
  float s = 0.f;
#pragma unroll
  for (int j = 0; j < 16; ++j) {
    float4 kv = *(const float4*)&Km[r][cb + j * 4];
    s += kv.x + kv.y + kv.z + kv.w;
  }
  for (int m = 1; m < 64; m <<= 1) s += __shfl_xor(s, m);
  if (l == 0) red[w] = s;
  __syncthreads();
  float mu = (red[0] + red[1] + red[2] + red[3]) * (1.f / 16384.f);
  __syncthreads();
  float q = 0.f;
#pragma unroll
  for (int j = 0; j < 16; ++j) {
    float4 kv = *(const float4*)&Km[r][cb + j * 4];
    float d0 = kv.x - mu, d1 = kv.y - mu, d2 = kv.z - mu, d3 = kv.w - mu;
    q += d0 * d0 + d1 * d1 + d2 * d2 + d3 * d3;
  }
  for (int m = 1; m < 64; m <<= 1) q += __shfl_xor(q, m);
  if (l == 0) red[w] = q;
  __syncthreads();
  float inv = rsqrtf((red[0] + red[1] + red[2] + red[3]) * (1.f / 16384.f) + 1e-5f);
#pragma unroll
  for (int j = 0; j < 16; ++j) {
    float4 kv = *(const float4*)&Km[r][cb + j * 4];
    kv.x = (kv.x - mu) * inv; kv.y = (kv.y - mu) * inv;
    kv.z = (kv.z - mu) * inv; kv.w = (kv.w - mu) * inv;
    *(float4*)&Km[r][cb + j * 4] = kv;
  }
  if (t < 128) { u_[t] = 0.f; v_[t] = 0.f; }
  __syncthreads();
  // 10 sinkhorn iterations (u/v potentials)
  for (int it = 0; it < 10; ++it) {
    float mx = -1e30f;
#pragma unroll
    for (int j = 0; j < 16; ++j) {
      float4 kv = *(const float4*)&Km[r][cb + j * 4];
      float4 vv = *(const float4*)&v_[cb + j * 4];
      mx = fmaxf(mx, fmaxf(fmaxf(kv.x - vv.x, kv.y - vv.y), fmaxf(kv.z - vv.z, kv.w - vv.w)));
    }
    mx = fmaxf(mx, __shfl_xor(mx, 1));
    float sm = 0.f;
#pragma unroll
    for (int j = 0; j < 16; ++j) {
      float4 kv = *(const float4*)&Km[r][cb + j * 4];
      float4 vv = *(const float4*)&v_[cb + j * 4];
      sm += __expf(kv.x - vv.x - mx) + __expf(kv.y - vv.y - mx)
          + __expf(kv.z - vv.z - mx) + __expf(kv.w - vv.w - mx);
    }
    sm += __shfl_xor(sm, 1);
    if (hf == 0) u_[r] = mx + __logf(sm);
    __syncthreads();
    int c = r;
    float mc = -1e30f;
#pragma unroll 16
    for (int i = 0; i < 64; ++i)
      mc = fmaxf(mc, Km[cb + i][c] - u_[cb + i]);
    mc = fmaxf(mc, __shfl_xor(mc, 1));
    float sc = 0.f;
#pragma unroll 16
    for (int i = 0; i < 64; ++i)
      sc += __expf(Km[cb + i][c] - u_[cb + i] - mc);
    sc += __shfl_xor(sc, 1);
    if (hf == 0) v_[c] = mc + __logf(sc);
    __syncthreads();
  }
  // focal loss
  float ur = u_[r];
  bool gt = (r < 64) == (hf == 0);
  float fs = 0.f;
#pragma unroll
  for (int j = 0; j < 16; ++j) {
    float4 kv = *(const float4*)&Km[r][cb + j * 4];
    float4 vv = *(const float4*)&v_[cb + j * 4];
    float x4[4] = {kv.x - vv.x, kv.y - vv.y, kv.z - vv.z, kv.w - vv.w};
#pragma unroll
    for (int q2 = 0; q2 < 4; ++q2) {
      float P = __expf(x4[q2] - ur);
      float pt = fminf(fmaxf(P, 1e-6f), 1.0f - 1e-6f);
      fs += gt ? (-0.25f * (1.f - pt) * (1.f - pt) * __logf(pt))
               : (-0.75f * pt * pt * __logf(1.f - pt));
    }
  }
  for (int m = 1; m < 64; m <<= 1) fs += __shfl_xor(fs, m);
  if (l == 0) red[w] = fs;
  __syncthreads();
  if (t == 0) {
    atomicAdd(acc + 1, (red[0] + red[1] + red[2] + red[3]) * (1.0f / 131072.f));
    ticket_finalize(acc, out);
  }
}

// ---------------- cls MLP + BCE: 4 rows per group, stride loop ----------------
__device__ void cls_dev(const u16* __restrict__ bufH, const u16* __restrict__ w1t,
                        const float* __restrict__ b1, const float* __restrict__ W2,
                        const float* __restrict__ b2, float* acc, float* out,
                        int bid, char* smc) {
  float (*xs)[256] = (float(*)[256])smc;
  float* red = (float*)(smc + 4096);
  int t = threadIdx.x, l = t & 63, w = t >> 6;
  float total = 0.f;
  float bb2 = b2[0];
  for (int g = bid - 8; g < 512; g += 504) {
    int row0 = g * 4;
    __syncthreads();
#pragma unroll
    for (int i = 0; i < 4; ++i) {
      int e = t + i * 256;
      xs[e >> 8][e & 255] = bf2f(bufH[(size_t)(row0 + (e >> 8)) * 256 + (e & 255)]);
    }
    __syncthreads();
    int col = t & 127, rp = t >> 7;
    const u16* wp = w1t + (size_t)col * 256;
    float h0 = 0.f, h1 = 0.f;
#pragma unroll
    for (int i = 0; i < 32; ++i) {
      u32x4 wv = *(const u32x4*)&wp[i * 8];
      const float* xa = &xs[rp][i * 8];
      const float* xb = &xs[rp + 2][i * 8];
      float w0 = bf2f(wv[0] & 0xffffu), w1 = bf2f(wv[0] >> 16);
      float w2_ = bf2f(wv[1] & 0xffffu), w3 = bf2f(wv[1] >> 16);
      float w4 = bf2f(wv[2] & 0xffffu), w5 = bf2f(wv[2] >> 16);
      float w6 = bf2f(wv[3] & 0xffffu), w7 = bf2f(wv[3] >> 16);
      h0 += xa[0]*w0 + xa[1]*w1 + xa[2]*w2_ + xa[3]*w3 + xa[4]*w4 + xa[5]*w5 + xa[6]*w6 + xa[7]*w7;
      h1 += xb[0]*w0 + xb[1]*w1 + xb[2]*w2_ + xb[3]*w3 + xb[4]*w4 + xb[5]*w5 + xb[6]*w6 + xb[7]*w7;
    }
    float b1c = b1[col], w2c = W2[col];
    float p0 = fmaxf(h0 + b1c, 0.f) * w2c;
    float p1 = fmaxf(h1 + b1c, 0.f) * w2c;
#pragma unroll
    for (int m = 1; m < 64; m <<= 1) { p0 += __shfl_xor(p0, m); p1 += __shfl_xor(p1, m); }
    if (l == 0) { red[w * 2] = p0; red[w * 2 + 1] = p1; }
    __syncthreads();
    if (t == 0) {
      float z0 = red[0] + red[2] + bb2;   // row0+0
      float z1 = red[4] + red[6] + bb2;   // row0+1
      float z2 = red[1] + red[3] + bb2;   // row0+2
      float z3 = red[5] + red[7] + bb2;   // row0+3
      float zz[4] = {z0, z1, z2, z3};
#pragma unroll
      for (int rr = 0; rr < 4; ++rr) {
        float z = zz[rr];
        float lab = (((row0 + rr) & 127) < 64) ? 1.f : 0.f;
        total += fmaxf(z, 0.f) - z * lab + log1pf(__expf(-fabsf(z)));
      }
    }
  }
  if (t == 0) {
    atomicAdd(acc, total * (1.0f / 1024.0f));
    ticket_finalize(acc, out);
  }
}

// ---------------- the mega kernel: everything after head, grid-synced ----------------
__global__ __launch_bounds__(256, 2) void mega_kernel(
    const float* __restrict__ feat_s, const float* __restrict__ feat_t,
    const int* __restrict__ idxb, u16* __restrict__ nodes,
    const u16* __restrict__ wt, const u16* __restrict__ w1t,
    const float* __restrict__ head_b1, const float* __restrict__ head_b2,
    const float* __restrict__ intra_b, const float* __restrict__ cross_b,
    const float* __restrict__ cls_b1, const float* __restrict__ cls_W2,
    const float* __restrict__ cls_b2,
    u16* bufA, u16* bufB, u16* bufH, u16* qkv, u16* attnb,
    float* st1, float* st2, float* acc, float* out_f) {
  __shared__ __align__(16) char SMEM[69248];
  int bid = blockIdx.x, t = threadIdx.x;
  int* bars = (int*)acc + 4;
  const u16* wt_h1 = wt;
  const u16* wt_h2 = wt + 131072;
  const u16* wt_in = wt_h2 + 65536;
  const u16* wt_cr = wt_in + 4 * 65536;
  const u16* wt_af = wt_cr + 4 * 65536;

  // P0: gather -> bf16 nodes (4 rows per block)
#pragma unroll
  for (int g = 0; g < 4; ++g) {
    int row = bid * 4 + g;
    int bi = row >> 7, n = row & 127, b = bi & 7;
    const float* fp = (bi < 8) ? feat_s : feat_t;
    int pos = idxb[bi * NN + n];
    const float* src = fp + (size_t)b * CENC * HW + pos;
    float f0 = src[(size_t)(2 * t) * HW];
    float f1 = src[(size_t)(2 * t + 1) * HW];
    ((unsigned*)(nodes + (size_t)row * CENC))[t] = pack2(f0, f1);
  }
  gbar(bars, 1);
  // P1: bufA = nodes @ W1 + b1, stats st1
  { int mt = bid >> 2, n0 = (bid & 3) << 6;
    gemm16x64(nodes, wt_h1, head_b1, bufA, nullptr, nullptr, 0, st1, mt * 16, n0, 512, SMEM); }
  gbar(bars, 2);
  // P2: bufB = relu(LN(bufA)) @ W2 + b2, stats st2
  { int mt = bid >> 2, n0 = (bid & 3) << 6;
    gemm16x64(bufA, wt_h2, head_b2, bufB, nullptr, st1, 1, st2, mt * 16, n0, 256, SMEM); }
  gbar(bars, 3);
  // P3: intra QKV from LN(bufB)
  for (int tau = bid; tau < 1536; tau += 512) {
    int z = tau >> 9, rr = tau & 511, mt = rr >> 2, n0 = (rr & 3) << 6;
    gemm16x64(bufB, wt_in + (size_t)z * 65536, intra_b + z * 256,
              qkv + (size_t)z * ROWS2 * DD, nullptr, st2, 0, nullptr, mt * 16, n0, 256, SMEM);
  }
  gbar(bars, 4);
  // P4: intra attention
  if (bid < 256) attn_dev(qkv, qkv + ROWS2 * DD, qkv + 2 * ROWS2 * DD, attnb, 0, bid, SMEM);
  gbar(bars, 5);
  // P5: bufH = attn @ Wo_intra + bo
  { int mt = bid >> 2, n0 = (bid & 3) << 6;
    gemm16x64(attnb, wt_in + 3 * 65536, intra_b + 768, bufH, nullptr, nullptr, 0, nullptr,
              mt * 16, n0, 256, SMEM); }
  gbar(bars, 6);
  // P6: cross QKV from bufH
  for (int tau = bid; tau < 1536; tau += 512) {
    int z = tau >> 9, rr = tau & 511, mt = rr >> 2, n0 = (rr & 3) << 6;
    gemm16x64(bufH, wt_cr + (size_t)z * 65536, cross_b + z * 256,
              qkv + (size_t)z * ROWS2 * DD, nullptr, nullptr, 0, nullptr, mt * 16, n0, 256, SMEM);
  }
  gbar(bars, 7);
  // P7: cross attention (swapped KV)
  if (bid < 256) attn_dev(qkv, qkv + ROWS2 * DD, qkv + 2 * ROWS2 * DD, attnb, 1, bid, SMEM);
  gbar(bars, 8);
  // P8: bufH = attn @ Wo_cross + bo  (+ n1 -> d_out for rows < 1024)
  { int mt = bid >> 2, n0 = (bid & 3) << 6;
    gemm16x64(attnb, wt_cr + 3 * 65536, cross_b + 768, bufH, out_f, nullptr, 0, nullptr,
              mt * 16, n0, 256, SMEM); }
  gbar(bars, 9);
  // P9: tail
  if (bid < 8) sinkhorn_dev(bufH, wt_af, acc, out_f, bid, SMEM);
  else         cls_dev(bufH, w1t, cls_b1, cls_W2, cls_b2, acc, out_f, bid, SMEM);
}

extern "C" void kernel_launch(void* const* d_in, const int* in_sizes, int n_in,
                              void* d_out, int out_size, void* d_ws, size_t ws_size,
                              hipStream_t stream) {
  const float* feat_s  = (const float*)d_in[0];
  const float* score_s = (const float*)d_in[1];
  const float* feat_t  = (const float*)d_in[2];
  const float* score_t = (const float*)d_in[3];
  const float* head_W1 = (const float*)d_in[4];
  const float* head_b1 = (const float*)d_in[5];
  const float* head_W2 = (const float*)d_in[6];
  const float* head_b2 = (const float*)d_in[7];
  const float* intra_W = (const float*)d_in[8];
  const float* intra_b = (const float*)d_in[9];
  const float* cross_W = (const float*)d_in[10];
  const float* cross_b = (const float*)d_in[11];
  const float* cls_W1  = (const float*)d_in[12];
  const float* cls_b1  = (const float*)d_in[13];
  const float* cls_W2  = (const float*)d_in[14];
  const float* cls_b2  = (const float*)d_in[15];
  const float* aff_A   = (const float*)d_in[16];

  u16* nodes = (u16*)d_ws;                       // 2048*512
  u16* bufA  = nodes + 2048 * 512;               // 2048*256
  u16* bufB  = bufA + ROWS2 * DD;
  u16* bufH  = bufB + ROWS2 * DD;
  u16* qkv   = bufH + ROWS2 * DD;                // 3 planes
  u16* attnb = qkv + 3 * ROWS2 * DD;
  u16* wt    = attnb + ROWS2 * DD;               // 786432
  u16* w1t   = wt + 786432;                      // 32768
  float* st1 = (float*)(w1t + 32768);            // 2048*32
  float* st2 = st1 + ROWS2 * 32;
  float* acc = st2 + ROWS2 * 32;                 // 32 floats: loss0,loss1,pad,ticket,bars[9]
  int* idxb  = (int*)(acc + 32);                 // 2048 ints
  float* out_f = (float*)d_out;

  head_kernel<<<832, 256, 0, stream>>>(score_s, score_t, idxb, acc,
                                       head_W1, head_W2, intra_W, cross_W, aff_A, cls_W1,
                                       wt, w1t);
  mega_kernel<<<NBLK, 256, 0, stream>>>(feat_s, feat_t, idxb, nodes, wt, w1t,
                                        head_b1, head_b2, intra_b, cross_b,
                                        cls_b1, cls_W2, cls_b2,
                                        bufA, bufB, bufH, qkv, attnb,
                                        st1, st2, acc, out_f);
}

// Round 9
// 758.044 us; speedup vs baseline: 1.1549x; 1.1549x over previous
//
#include <hip/hip_runtime.h>
#include <math.h>

#define BIMG 8
#define HW 9216
#define CENC 512
#define NN 128
#define DD 256
#define NHEAD 8
#define DH 32
#define ROWS1 1024
#define ROWS2 2048
#define NBLK 512

typedef unsigned long long ull;
typedef unsigned short u16;
typedef __attribute__((ext_vector_type(4))) float f32x4;
typedef __attribute__((ext_vector_type(4))) unsigned u32x4;
typedef __attribute__((ext_vector_type(2))) unsigned u32x2;

__device__ __forceinline__ u16 f2bf(float f) {
  unsigned u = __float_as_uint(f);
  u += 0x7fffu + ((u >> 16) & 1u);
  return (u16)(u >> 16);
}
__device__ __forceinline__ float bf2f(unsigned h) { return __uint_as_float(h << 16); }
__device__ __forceinline__ unsigned pack2(float a, float b) {
  return (unsigned)f2bf(a) | ((unsigned)f2bf(b) << 16);
}
__device__ __forceinline__ void mfma_b(f32x4& acc, u32x4 a, u32x4 b) {
  asm volatile("v_mfma_f32_16x16x32_bf16 %0, %1, %2, %0" : "+v"(acc) : "v"(a), "v"(b));
}

__device__ __forceinline__ ull cmpex_keep(ull k, ull o, bool keepMax) {
  return ((k > o) == keepMax) ? k : o;
}
__device__ __forceinline__ void bsort64(ull& k, int lane) {
#pragma unroll
  for (int size = 2; size <= 64; size <<= 1) {
#pragma unroll
    for (int stride = size >> 1; stride > 0; stride >>= 1) {
      ull o = __shfl_xor(k, stride);
      bool keepMax = (((lane & size) == 0) == ((lane & stride) == 0));
      k = cmpex_keep(k, o, keepMax);
    }
  }
}
__device__ __forceinline__ void bmerge64(ull& top, ull b, int lane) {
  ull rev = __shfl_xor(b, 63);
  ull m = top > rev ? top : rev;
#pragma unroll
  for (int stride = 32; stride > 0; stride >>= 1) {
    ull o = __shfl_xor(m, stride);
    m = cmpex_keep(m, o, (lane & stride) == 0);
  }
  top = m;
}

// ---- launch 1: 0..31 top-64 ; 32..799 weight transpose ; 800..831 cls_W1 -> bf16 ----
__global__ __launch_bounds__(256) void head_kernel(const float* __restrict__ score_s,
                                                   const float* __restrict__ score_t,
                                                   int* __restrict__ idx_out,
                                                   float* __restrict__ loss_acc,
                                                   const float* __restrict__ hw1,
                                                   const float* __restrict__ hw2,
                                                   const float* __restrict__ iw,
                                                   const float* __restrict__ cw,
                                                   const float* __restrict__ aw,
                                                   const float* __restrict__ clsW1,
                                                   u16* __restrict__ wt,
                                                   u16* __restrict__ w1t) {
  __shared__ ull sm[256];
  __shared__ float tile[32][33];
  int tid = threadIdx.x;
  if (blockIdx.x < 32) {
    int blk = blockIdx.x;
    int bi = blk >> 1, neg = blk & 1;
    int lane = tid & 63, w = tid >> 6;
    if (blk == 0) ((unsigned*)loss_acc)[tid] = 0u;  // zero losses/ticket/barrier lines (1 KB)
    const float* sp = (bi < 8 ? score_s : score_t) + (size_t)(bi & 7) * HW;
    int q0 = w * 36;
    ull keys[36];
#pragma unroll
    for (int j = 0; j < 36; ++j) {
      float x = sp[(q0 + j) * 64 + lane];
      unsigned ub = __float_as_uint(x);
      unsigned u = (ub & 0x80000000u) ? ~ub : (ub | 0x80000000u);
      if (neg) u = ~u;
      int gi = (q0 + j) * 64 + lane;
      keys[j] = ((ull)u << 32) | (unsigned)(~gi);
    }
    ull top1 = keys[0];  bsort64(top1, lane);
    ull top2 = keys[18]; bsort64(top2, lane);
#pragma unroll
    for (int j = 1; j < 18; ++j) {
      ull k1 = keys[j], k2 = keys[18 + j];
      bsort64(k1, lane);
      bsort64(k2, lane);
      bmerge64(top1, k1, lane);
      bmerge64(top2, k2, lane);
    }
    bmerge64(top1, top2, lane);
    sm[w * 64 + lane] = top1;
    __syncthreads();
    if (w < 2) {
      ull a = sm[(2 * w) * 64 + lane];
      ull b = sm[(2 * w + 1) * 64 + (63 - lane)];
      ull m = a > b ? a : b;
#pragma unroll
      for (int stride = 32; stride > 0; stride >>= 1) {
        ull o = __shfl_xor(m, stride);
        m = cmpex_keep(m, o, (lane & stride) == 0);
      }
      sm[(2 * w) * 64 + lane] = m;
    }
    __syncthreads();
    if (w == 0) {
      ull a = sm[lane];
      ull b = sm[128 + (63 - lane)];
      ull m = a > b ? a : b;
#pragma unroll
      for (int stride = 32; stride > 0; stride >>= 1) {
        ull o = __shfl_xor(m, stride);
        m = cmpex_keep(m, o, (lane & stride) == 0);
      }
      idx_out[bi * NN + neg * 64 + lane] = (int)(~(unsigned)(m & 0xffffffffull));
    }
  } else if (blockIdx.x < 800) {
    int bid = blockIdx.x - 32;
    const float* src; u16* dst; int K, k0, n0;
    if (bid < 128) {
      src = hw1; dst = wt; K = 512;
      k0 = (bid >> 3) * 32; n0 = (bid & 7) * 32;
    } else {
      int id2 = bid - 128;
      int m = id2 >> 6, tt = id2 & 63;
      K = 256;
      k0 = (tt >> 3) * 32; n0 = (tt & 7) * 32;
      src = (m == 0) ? hw2 : (m < 5) ? iw + (size_t)(m - 1) * 65536
          : (m < 9) ? cw + (size_t)(m - 5) * 65536 : aw;
      dst = wt + 131072 + (size_t)m * 65536;
    }
    int r = tid >> 3, c = (tid & 7) * 4;
    float4 v = *(const float4*)&src[(size_t)(k0 + r) * 256 + n0 + c];
    tile[r][c] = v.x; tile[r][c + 1] = v.y; tile[r][c + 2] = v.z; tile[r][c + 3] = v.w;
    __syncthreads();
    u32x2 o;
    o[0] = pack2(tile[c][r], tile[c + 1][r]);
    o[1] = pack2(tile[c + 2][r], tile[c + 3][r]);
    *(u32x2*)&dst[(size_t)(n0 + r) * K + k0 + c] = o;
  } else {
    int bid3 = blockIdx.x - 800;     // cls_W1 [256][128] -> bf16 [128][256]
    int k0 = (bid3 >> 2) * 32, n0 = (bid3 & 3) * 32;
    int r = tid >> 3, c = (tid & 7) * 4;
    float4 v = *(const float4*)&clsW1[(size_t)(k0 + r) * 128 + n0 + c];
    tile[r][c] = v.x; tile[r][c + 1] = v.y; tile[r][c + 2] = v.z; tile[r][c + 3] = v.w;
    __syncthreads();
    u32x2 o;
    o[0] = pack2(tile[c][r], tile[c + 1][r]);
    o[1] = pack2(tile[c + 2][r], tile[c + 3][r]);
    *(u32x2*)&w1t[(size_t)(n0 + r) * 256 + k0 + c] = o;
  }
}

// ---------------- coherent spin read: bypass L1 and per-XCD L2 ----------------
__device__ __forceinline__ int spin_ld(const int* p) {
  int v;
  asm volatile("global_load_dword %0, %1, off sc0 sc1\n\ts_waitcnt vmcnt(0)"
               : "=v"(v) : "v"(p) : "memory");
  return v;
}

// ---- grid barrier: 8 padded arrival counters (own cache lines) + padded master ----
__device__ __forceinline__ void gbar(int* bars, int phase) {
  __syncthreads();
  if (threadIdx.x == 0) {
    __threadfence();                       // release: write back this XCD's L2
    int sub = blockIdx.x & 7;
    int v = atomicAdd(&bars[sub * 16], 1) + 1;      // device-scope RMW (m20)
    if (v == (NBLK / 8) * phase)
      atomicAdd(&bars[128], 1);
    while (spin_ld(&bars[128]) < 8 * phase)
      __builtin_amdgcn_s_sleep(32);
  }
  __syncthreads();
  __threadfence();                         // acquire: invalidate stale cache lines
}

__device__ __forceinline__ void ticket_finalize(float* acc, float* out) {
  __threadfence();
  int tk = atomicAdd((int*)acc + 3, 1);
  if (tk == NBLK - 1) {
    float a0 = atomicAdd(acc + 0, 0.0f);
    float a1 = atomicAdd(acc + 1, 0.0f);
    out[ROWS1 * DD] = a0 + 10.0f * a1;
  }
}

// ---------------- 16x64 MFMA GEMM tile, K chunked by 256, LNopt on A ----------------
__device__ void gemm16x64(const u16* __restrict__ A, const u16* __restrict__ Wt,
                          const float* __restrict__ bias, u16* Cb, float* Cf,
                          const float* sin, int relu, float* sout,
                          int m0, int n0, int K, char* smc) {
  u16 (*As)[264] = (u16(*)[264])smc;
  u16 (*Bs)[264] = (u16(*)[264])(smc + 16 * 264 * 2);
  float* mS = (float*)(smc + 80 * 264 * 2);
  float* rS = mS + 16;
  int t = threadIdx.x, l = t & 63, w = t >> 6;
  if (sin) {
    if (t < 16) {
      const float* sp = sin + (size_t)(m0 + t) * 32;
      float s = 0.f, q = 0.f;
#pragma unroll
      for (int i = 0; i < 16; ++i) { s += sp[i]; q += sp[16 + i]; }
      float mm = s * (1.f / 256.f);
      mS[t] = mm;
      rS[t] = rsqrtf(fmaxf(q * (1.f / 256.f) - mm * mm, 0.f) + 1e-5f);
    }
    __syncthreads();
  }
  f32x4 acc = {0.f, 0.f, 0.f, 0.f};
  for (int ch = 0; ch < K; ch += 256) {
#pragma unroll
    for (int i = 0; i < 2; ++i) {
      int e = t + i * 256;
      int row = e >> 5, c8 = (e & 31) * 8;
      u32x4 av = *(const u32x4*)&A[(size_t)(m0 + row) * K + ch + c8];
      if (sin) {
        float mm = mS[row], rr = rS[row];
#pragma unroll
        for (int j = 0; j < 4; ++j) {
          float f0 = (bf2f(av[j] & 0xffffu) - mm) * rr;
          float f1 = (bf2f(av[j] >> 16) - mm) * rr;
          if (relu) { f0 = fmaxf(f0, 0.f); f1 = fmaxf(f1, 0.f); }
          av[j] = pack2(f0, f1);
        }
      }
      *(u32x4*)&As[row][c8] = av;
    }
#pragma unroll
    for (int i = 0; i < 8; ++i) {
      int e = t + i * 256;
      int row = e >> 5, c8 = (e & 31) * 8;
      *(u32x4*)&Bs[row][c8] = *(const u32x4*)&Wt[(size_t)(n0 + row) * K + ch + c8];
    }
    __syncthreads();
    int fra = l & 15, frk = (l >> 4) * 8, fbn = w * 16 + (l & 15);
#pragma unroll
    for (int ks = 0; ks < 8; ++ks) {
      u32x4 af = *(const u32x4*)&As[fra][ks * 32 + frk];
      u32x4 bf = *(const u32x4*)&Bs[fbn][ks * 32 + frk];
      mfma_b(acc, af, bf);
    }
    __syncthreads();
  }
  asm volatile("s_nop 7\n\ts_nop 7" ::);
  int col0 = n0 + w * 16 + (l & 15);
  float bb = bias ? bias[col0] : 0.f;
  int slot = (n0 >> 4) + w;
#pragma unroll
  for (int r = 0; r < 4; ++r) {
    int row = m0 + (l >> 4) * 4 + r;
    float o = acc[r] + bb;
    if (Cb) Cb[(size_t)row * 256 + col0] = f2bf(o);
    if (Cf && row < ROWS1) Cf[(size_t)row * 256 + col0] = o;
    if (sout) {
      float s = o, q = o * o;
#pragma unroll
      for (int m = 1; m < 16; m <<= 1) { s += __shfl_xor(s, m); q += __shfl_xor(q, m); }
      if ((l & 15) == 0) {
        sout[(size_t)row * 32 + slot] = s;
        sout[(size_t)row * 32 + 16 + slot] = q;
      }
    }
  }
}

// ---------------- attention (64 q-rows per logical blk, 4 j-quarters) ----------------
__device__ void attn_dev(const u16* __restrict__ q, const u16* __restrict__ k,
                         const u16* __restrict__ v, u16* __restrict__ o,
                         int swap, int blk, char* smc) {
  float (*Ks)[DH] = (float(*)[DH])smc;
  float (*Vs)[DH] = (float(*)[DH])(smc + 16384);
  float (*Ex)[3][34] = (float(*)[3][34])(smc + 32768);
  int bb = blk >> 4, h = (blk >> 1) & 7, qh = blk & 1;
  int kb = swap ? (bb ^ 8) : bb;
  int t = threadIdx.x;
  int rr = t & 63, part = t >> 6;
  for (int e = t; e < 1024; e += 256) {
    int which = e >> 9;
    int idx2 = e & 511;
    int r = idx2 >> 2, c8 = (idx2 & 3) * 8;
    u32x4 val = *(const u32x4*)&(which ? v : k)[(size_t)(kb * NN + r) * DD + h * DH + c8];
    float* dst = which ? &Vs[r][c8] : &Ks[r][c8];
#pragma unroll
    for (int i = 0; i < 4; ++i) {
      dst[2 * i]     = bf2f(val[i] & 0xffffu);
      dst[2 * i + 1] = bf2f(val[i] >> 16);
    }
  }
  __syncthreads();
  int qrow = bb * NN + qh * 64 + rr;
  float4 q4[8];
  {
    const u16* qp = q + (size_t)qrow * DD + h * DH;
#pragma unroll
    for (int c4 = 0; c4 < 4; ++c4) {
      u32x4 u = *(const u32x4*)&qp[c4 * 8];
      q4[c4 * 2].x = bf2f(u[0] & 0xffffu); q4[c4 * 2].y = bf2f(u[0] >> 16);
      q4[c4 * 2].z = bf2f(u[1] & 0xffffu); q4[c4 * 2].w = bf2f(u[1] >> 16);
      q4[c4 * 2 + 1].x = bf2f(u[2] & 0xffffu); q4[c4 * 2 + 1].y = bf2f(u[2] >> 16);
      q4[c4 * 2 + 1].z = bf2f(u[3] & 0xffffu); q4[c4 * 2 + 1].w = bf2f(u[3] >> 16);
    }
  }
  const float scale = 0.17677669529663687f;
  int j0 = part * 32;
  float mx = -1e30f;
  for (int j = j0; j < j0 + 32; ++j) {
    const float4* kp = (const float4*)Ks[j];
    float s = 0.f;
#pragma unroll
    for (int c4 = 0; c4 < 8; ++c4) {
      float4 kv = kp[c4];
      s += q4[c4].x * kv.x + q4[c4].y * kv.y + q4[c4].z * kv.z + q4[c4].w * kv.w;
    }
    mx = fmaxf(mx, s * scale);
  }
  float acc[DH];
#pragma unroll
  for (int c = 0; c < DH; ++c) acc[c] = 0.f;
  float den = 0.f;
  for (int j = j0; j < j0 + 32; ++j) {
    const float4* kp = (const float4*)Ks[j];
    float s = 0.f;
#pragma unroll
    for (int c4 = 0; c4 < 8; ++c4) {
      float4 kv = kp[c4];
      s += q4[c4].x * kv.x + q4[c4].y * kv.y + q4[c4].z * kv.z + q4[c4].w * kv.w;
    }
    float e = __expf(s * scale - mx);
    den += e;
    const float4* vp = (const float4*)Vs[j];
#pragma unroll
    for (int c4 = 0; c4 < 8; ++c4) {
      float4 vv = vp[c4];
      acc[c4 * 4 + 0] += e * vv.x; acc[c4 * 4 + 1] += e * vv.y;
      acc[c4 * 4 + 2] += e * vv.z; acc[c4 * 4 + 3] += e * vv.w;
    }
  }
  if (part) {
#pragma unroll
    for (int c = 0; c < DH; ++c) Ex[rr][part - 1][c] = acc[c];
    Ex[rr][part - 1][32] = mx;
    Ex[rr][part - 1][33] = den;
  }
  __syncthreads();
  if (part == 0) {
    float M = mx;
#pragma unroll
    for (int p = 0; p < 3; ++p) M = fmaxf(M, Ex[rr][p][32]);
    float f0 = __expf(mx - M);
    float fp[3];
    float dt = den * f0;
#pragma unroll
    for (int p = 0; p < 3; ++p) { fp[p] = __expf(Ex[rr][p][32] - M); dt += Ex[rr][p][33] * fp[p]; }
    float inv = 1.0f / dt;
    unsigned ovu[16];
#pragma unroll
    for (int c = 0; c < 16; ++c) {
      float x0 = acc[2 * c] * f0, x1 = acc[2 * c + 1] * f0;
#pragma unroll
      for (int p = 0; p < 3; ++p) { x0 += Ex[rr][p][2 * c] * fp[p]; x1 += Ex[rr][p][2 * c + 1] * fp[p]; }
      ovu[c] = pack2(x0 * inv, x1 * inv);
    }
    unsigned* op = (unsigned*)(o + (size_t)qrow * DD + h * DH);
#pragma unroll
    for (int i = 0; i < 4; ++i) {
      u32x4 w4;
      w4[0] = ovu[4 * i]; w4[1] = ovu[4 * i + 1]; w4[2] = ovu[4 * i + 2]; w4[3] = ovu[4 * i + 3];
      *(u32x4*)&op[4 * i] = w4;
    }
  }
}

// ---------------- sinkhorn per image pair (256 threads) ----------------
__device__ void sinkhorn_dev(const u16* __restrict__ bufH, const u16* __restrict__ wt_af,
                             float* acc, float* out, int b, char* smc) {
  u16 (*tmpL)[264] = (u16(*)[264])smc;
  float (*Km)[133] = (float(*)[133])smc;
  float* u_ = (float*)(smc + 68096);
  float* v_ = u_ + 128;
  float* red = v_ + 128;
  int t = threadIdx.x, l = t & 63, w = t >> 6;
  const u16* c1 = bufH + (size_t)(b * 128) * 256;
  const u16* c2 = bufH + (size_t)(1024 + b * 128) * 256;
  for (int ch = 0; ch < 2; ++ch) {
    f32x4 a2[2][8];
#pragma unroll
    for (int rt = 0; rt < 2; ++rt)
#pragma unroll
      for (int i = 0; i < 8; ++i) a2[rt][i] = (f32x4){0.f, 0.f, 0.f, 0.f};
#pragma unroll
    for (int ks = 0; ks < 8; ++ks) {
      int kk = ks * 32 + (l >> 4) * 8;
      u32x4 a0 = *(const u32x4*)&c1[(size_t)(w * 32 + (l & 15)) * 256 + kk];
      u32x4 a1 = *(const u32x4*)&c1[(size_t)(w * 32 + 16 + (l & 15)) * 256 + kk];
#pragma unroll
      for (int i = 0; i < 8; ++i) {
        u32x4 bf = *(const u32x4*)&wt_af[(size_t)(ch * 128 + i * 16 + (l & 15)) * 256 + kk];
        mfma_b(a2[0][i], a0, bf);
        mfma_b(a2[1][i], a1, bf);
      }
    }
    asm volatile("s_nop 7\n\ts_nop 7" ::);
#pragma unroll
    for (int rt = 0; rt < 2; ++rt)
#pragma unroll
      for (int i = 0; i < 8; ++i) {
        int col = ch * 128 + i * 16 + (l & 15);
        int rb = w * 32 + rt * 16 + (l >> 4) * 4;
#pragma unroll
        for (int r2 = 0; r2 < 4; ++r2)
          tmpL[rb + r2][col] = f2bf(a2[rt][i][r2]);
      }
  }
  __syncthreads();
  f32x4 aB[2][8];
#pragma unroll
  for (int rt = 0; rt < 2; ++rt)
#pragma unroll
    for (int i = 0; i < 8; ++i) aB[rt][i] = (f32x4){0.f, 0.f, 0.f, 0.f};
#pragma unroll
  for (int ks = 0; ks < 8; ++ks) {
    int kk = ks * 32 + (l >> 4) * 8;
    u32x4 a0 = *(const u32x4*)&tmpL[w * 32 + (l & 15)][kk];
    u32x4 a1 = *(const u32x4*)&tmpL[w * 32 + 16 + (l & 15)][kk];
#pragma unroll
    for (int i = 0; i < 8; ++i) {
      u32x4 bf = *(const u32x4*)&c2[(size_t)(i * 16 + (l & 15)) * 256 + kk];
      mfma_b(aB[0][i], a0, bf);
      mfma_b(aB[1][i], a1, bf);
    }
  }
  asm volatile("s_nop 7\n\ts_nop 7" ::);
  __syncthreads();
#pragma unroll
  for (int rt = 0; rt < 2; ++rt)
#pragma unroll
    for (int i = 0; i < 8; ++i) {
      int col = i * 16 + (l & 15);
      int rb = w * 32 + rt * 16 + (l >> 4) * 4;
#pragma unroll
      for (int r2 = 0; r2 < 4; ++r2)
        Km[rb + r2][col] = aB[rt][i][r2];
    }
  __syncthreads();
  int r = t >> 1, hf = t & 1, cb = hf * 64;
  float s = 0.f;
#pragma unroll
  for (int j = 0; j < 16; ++j) {
    float4 kv = *(const float4*)&Km[r][cb + j * 4];
    s += kv.x + kv.y + kv.z + kv.w;
  }
  for (int m = 1; m < 64; m <<= 1) s += __shfl_xor(s, m);
  if (l == 0) red[w] = s;
  __syncthreads();
  float mu = (red[0] + red[1] + red[2] + red[3]) * (1.f / 16384.f);
  __syncthreads();
  float q = 0.f;
#pragma unroll
  for (int j = 0; j < 16; ++j) {
    float4 kv = *(const float4*)&Km[r][cb + j * 4];
    float d0 = kv.x - mu, d1 = kv.y - mu, d2 = kv.z - mu, d3 = kv.w - mu;
    q += d0 * d0 + d1 * d1 + d2 * d2 + d3 * d3;
  }
  for (int m = 1; m < 64; m <<= 1) q += __shfl_xor(q, m);
  if (l == 0) red[w] = q;
  __syncthreads();
  float inv = rsqrtf((red[0] + red[1] + red[2] + red[3]) * (1.f / 16384.f) + 1e-5f);
#pragma unroll
  for (int j = 0; j < 16; ++j) {
    float4 kv = *(const float4*)&Km[r][cb + j * 4];
    kv.x = (kv.x - mu) * inv; kv.y = (kv.y - mu) * inv;
    kv.z = (kv.z - mu) * inv; kv.w = (kv.w - mu) * inv;
    *(float4*)&Km[r][cb + j * 4] = kv;
  }
  if (t < 128) { u_[t] = 0.f; v_[t] = 0.f; }
  __syncthreads();
  for (int it = 0; it < 10; ++it) {
    float mx = -1e30f;
#pragma unroll
    for (int j = 0; j < 16; ++j) {
      float4 kv = *(const float4*)&Km[r][cb + j * 4];
      float4 vv = *(const float4*)&v_[cb + j * 4];
      mx = fmaxf(mx, fmaxf(fmaxf(kv.x - vv.x, kv.y - vv.y), fmaxf(kv.z - vv.z, kv.w - vv.w)));
    }
    mx = fmaxf(mx, __shfl_xor(mx, 1));
    float sm = 0.f;
#pragma unroll
    for (int j = 0; j < 16; ++j) {
      float4 kv = *(const float4*)&Km[r][cb + j * 4];
      float4 vv = *(const float4*)&v_[cb + j * 4];
      sm += __expf(kv.x - vv.x - mx) + __expf(kv.y - vv.y - mx)
          + __expf(kv.z - vv.z - mx) + __expf(kv.w - vv.w - mx);
    }
    sm += __shfl_xor(sm, 1);
    if (hf == 0) u_[r] = mx + __logf(sm);
    __syncthreads();
    int c = r;
    float mc = -1e30f;
#pragma unroll 16
    for (int i = 0; i < 64; ++i)
      mc = fmaxf(mc, Km[cb + i][c] - u_[cb + i]);
    mc = fmaxf(mc, __shfl_xor(mc, 1));
    float sc = 0.f;
#pragma unroll 16
    for (int i = 0; i < 64; ++i)
      sc += __expf(Km[cb + i][c] - u_[cb + i] - mc);
    sc += __shfl_xor(sc, 1);
    if (hf == 0) v_[c] = mc + __logf(sc);
    __syncthreads();
  }
  float ur = u_[r];
  bool gt = (r < 64) == (hf == 0);
  float fs = 0.f;
#pragma unroll
  for (int j = 0; j < 16; ++j) {
    float4 kv = *(const float4*)&Km[r][cb + j * 4];
    float4 vv = *(const float4*)&v_[cb + j * 4];
    float x4[4] = {kv.x - vv.x, kv.y - vv.y, kv.z - vv.z, kv.w - vv.w};
#pragma unroll
    for (int q2 = 0; q2 < 4; ++q2) {
      float P = __expf(x4[q2] - ur);
      float pt = fminf(fmaxf(P, 1e-6f), 1.0f - 1e-6f);
      fs += gt ? (-0.25f * (1.f - pt) * (1.f - pt) * __logf(pt))
               : (-0.75f * pt * pt * __logf(1.f - pt));
    }
  }
  for (int m = 1; m < 64; m <<= 1) fs += __shfl_xor(fs, m);
  if (l == 0) red[w] = fs;
  __syncthreads();
  if (t == 0) {
    atomicAdd(acc + 1, (red[0] + red[1] + red[2] + red[3]) * (1.0f / 131072.f));
    ticket_finalize(acc, out);
  }
}

// ---------------- cls MLP + BCE: 4 rows per group, stride loop ----------------
__device__ void cls_dev(const u16* __restrict__ bufH, const u16* __restrict__ w1t,
                        const float* __restrict__ b1, const float* __restrict__ W2,
                        const float* __restrict__ b2, float* acc, float* out,
                        int bid, char* smc) {
  float (*xs)[256] = (float(*)[256])smc;
  float* red = (float*)(smc + 4096);
  int t = threadIdx.x, l = t & 63, w = t >> 6;
  float total = 0.f;
  float bb2 = b2[0];
  for (int g = bid - 8; g < 512; g += 504) {
    int row0 = g * 4;
    __syncthreads();
#pragma unroll
    for (int i = 0; i < 4; ++i) {
      int e = t + i * 256;
      xs[e >> 8][e & 255] = bf2f(bufH[(size_t)(row0 + (e >> 8)) * 256 + (e & 255)]);
    }
    __syncthreads();
    int col = t & 127, rp = t >> 7;
    const u16* wp = w1t + (size_t)col * 256;
    float h0 = 0.f, h1 = 0.f;
#pragma unroll
    for (int i = 0; i < 32; ++i) {
      u32x4 wv = *(const u32x4*)&wp[i * 8];
      const float* xa = &xs[rp][i * 8];
      const float* xb = &xs[rp + 2][i * 8];
      float w0 = bf2f(wv[0] & 0xffffu), w1 = bf2f(wv[0] >> 16);
      float w2_ = bf2f(wv[1] & 0xffffu), w3 = bf2f(wv[1] >> 16);
      float w4 = bf2f(wv[2] & 0xffffu), w5 = bf2f(wv[2] >> 16);
      float w6 = bf2f(wv[3] & 0xffffu), w7 = bf2f(wv[3] >> 16);
      h0 += xa[0]*w0 + xa[1]*w1 + xa[2]*w2_ + xa[3]*w3 + xa[4]*w4 + xa[5]*w5 + xa[6]*w6 + xa[7]*w7;
      h1 += xb[0]*w0 + xb[1]*w1 + xb[2]*w2_ + xb[3]*w3 + xb[4]*w4 + xb[5]*w5 + xb[6]*w6 + xb[7]*w7;
    }
    float b1c = b1[col], w2c = W2[col];
    float p0 = fmaxf(h0 + b1c, 0.f) * w2c;
    float p1 = fmaxf(h1 + b1c, 0.f) * w2c;
#pragma unroll
    for (int m = 1; m < 64; m <<= 1) { p0 += __shfl_xor(p0, m); p1 += __shfl_xor(p1, m); }
    if (l == 0) { red[w * 2] = p0; red[w * 2 + 1] = p1; }
    __syncthreads();
    if (t == 0) {
      float z0 = red[0] + red[2] + bb2;
      float z1 = red[4] + red[6] + bb2;
      float z2 = red[1] + red[3] + bb2;
      float z3 = red[5] + red[7] + bb2;
      float zz[4] = {z0, z1, z2, z3};
#pragma unroll
      for (int rr = 0; rr < 4; ++rr) {
        float z = zz[rr];
        float lab = (((row0 + rr) & 127) < 64) ? 1.f : 0.f;
        total += fmaxf(z, 0.f) - z * lab + log1pf(__expf(-fabsf(z)));
      }
    }
  }
  if (t == 0) {
    atomicAdd(acc, total * (1.0f / 1024.0f));
    ticket_finalize(acc, out);
  }
}

// ---------------- the mega kernel: everything after head, grid-synced ----------------
__global__ __launch_bounds__(256, 2) void mega_kernel(
    const float* __restrict__ feat_s, const float* __restrict__ feat_t,
    const int* __restrict__ idxb, u16* __restrict__ nodes,
    const u16* __restrict__ wt, const u16* __restrict__ w1t,
    const float* __restrict__ head_b1, const float* __restrict__ head_b2,
    const float* __restrict__ intra_b, const float* __restrict__ cross_b,
    const float* __restrict__ cls_b1, const float* __restrict__ cls_W2,
    const float* __restrict__ cls_b2,
    u16* bufA, u16* bufB, u16* bufH, u16* qkv, u16* attnb,
    float* st1, float* st2, float* acc, float* out_f) {
  __shared__ __align__(16) char SMEM[69248];
  int bid = blockIdx.x, t = threadIdx.x;
  int* bars = (int*)acc + 16;    // 8 padded sub-counters at bars[i*16], master at bars[128]
  const u16* wt_h1 = wt;
  const u16* wt_h2 = wt + 131072;
  const u16* wt_in = wt_h2 + 65536;
  const u16* wt_cr = wt_in + 4 * 65536;
  const u16* wt_af = wt_cr + 4 * 65536;

  // P0: gather -> bf16 nodes (4 rows per block)
#pragma unroll
  for (int g = 0; g < 4; ++g) {
    int row = bid * 4 + g;
    int bi = row >> 7, n = row & 127, b = bi & 7;
    const float* fp = (bi < 8) ? feat_s : feat_t;
    int pos = idxb[bi * NN + n];
    const float* src = fp + (size_t)b * CENC * HW + pos;
    float f0 = src[(size_t)(2 * t) * HW];
    float f1 = src[(size_t)(2 * t + 1) * HW];
    ((unsigned*)(nodes + (size_t)row * CENC))[t] = pack2(f0, f1);
  }
  gbar(bars, 1);
  // P1: bufA = nodes @ W1 + b1, stats st1
  { int mt = bid >> 2, n0 = (bid & 3) << 6;
    gemm16x64(nodes, wt_h1, head_b1, bufA, nullptr, nullptr, 0, st1, mt * 16, n0, 512, SMEM); }
  gbar(bars, 2);
  // P2: bufB = relu(LN(bufA)) @ W2 + b2, stats st2
  { int mt = bid >> 2, n0 = (bid & 3) << 6;
    gemm16x64(bufA, wt_h2, head_b2, bufB, nullptr, st1, 1, st2, mt * 16, n0, 256, SMEM); }
  gbar(bars, 3);
  // P3: intra QKV from LN(bufB)
  for (int tau = bid; tau < 1536; tau += 512) {
    int z = tau >> 9, rr = tau & 511, mt = rr >> 2, n0 = (rr & 3) << 6;
    gemm16x64(bufB, wt_in + (size_t)z * 65536, intra_b + z * 256,
              qkv + (size_t)z * ROWS2 * DD, nullptr, st2, 0, nullptr, mt * 16, n0, 256, SMEM);
  }
  gbar(bars, 4);
  // P4: intra attention
  if (bid < 256) attn_dev(qkv, qkv + ROWS2 * DD, qkv + 2 * ROWS2 * DD, attnb, 0, bid, SMEM);
  gbar(bars, 5);
  // P5: bufH = attn @ Wo_intra + bo
  { int mt = bid >> 2, n0 = (bid & 3) << 6;
    gemm16x64(attnb, wt_in + 3 * 65536, intra_b + 768, bufH, nullptr, nullptr, 0, nullptr,
              mt * 16, n0, 256, SMEM); }
  gbar(bars, 6);
  // P6: cross QKV from bufH
  for (int tau = bid; tau < 1536; tau += 512) {
    int z = tau >> 9, rr = tau & 511, mt = rr >> 2, n0 = (rr & 3) << 6;
    gemm16x64(bufH, wt_cr + (size_t)z * 65536, cross_b + z * 256,
              qkv + (size_t)z * ROWS2 * DD, nullptr, nullptr, 0, nullptr, mt * 16, n0, 256, SMEM);
  }
  gbar(bars, 7);
  // P7: cross attention (swapped KV)
  if (bid < 256) attn_dev(qkv, qkv + ROWS2 * DD, qkv + 2 * ROWS2 * DD, attnb, 1, bid, SMEM);
  gbar(bars, 8);
  // P8: bufH = attn @ Wo_cross + bo  (+ n1 -> d_out for rows < 1024)
  { int mt = bid >> 2, n0 = (bid & 3) << 6;
    gemm16x64(attnb, wt_cr + 3 * 65536, cross_b + 768, bufH, out_f, nullptr, 0, nullptr,
              mt * 16, n0, 256, SMEM); }
  gbar(bars, 9);
  // P9: tail
  if (bid < 8) sinkhorn_dev(bufH, wt_af, acc, out_f, bid, SMEM);
  else         cls_dev(bufH, w1t, cls_b1, cls_W2, cls_b2, acc, out_f, bid, SMEM);
}

extern "C" void kernel_launch(void* const* d_in, const int* in_sizes, int n_in,
                              void* d_out, int out_size, void* d_ws, size_t ws_size,
                              hipStream_t stream) {
  const float* feat_s  = (const float*)d_in[0];
  const float* score_s = (const float*)d_in[1];
  const float* feat_t  = (const float*)d_in[2];
  const float* score_t = (const float*)d_in[3];
  const float* head_W1 = (const float*)d_in[4];
  const float* head_b1 = (const float*)d_in[5];
  const float* head_W2 = (const float*)d_in[6];
  const float* head_b2 = (const float*)d_in[7];
  const float* intra_W = (const float*)d_in[8];
  const float* intra_b = (const float*)d_in[9];
  const float* cross_W = (const float*)d_in[10];
  const float* cross_b = (const float*)d_in[11];
  const float* cls_W1  = (const float*)d_in[12];
  const float* cls_b1  = (const float*)d_in[13];
  const float* cls_W2  = (const float*)d_in[14];
  const float* cls_b2  = (const float*)d_in[15];
  const float* aff_A   = (const float*)d_in[16];

  u16* nodes = (u16*)d_ws;                       // 2048*512
  u16* bufA  = nodes + 2048 * 512;               // 2048*256
  u16* bufB  = bufA + ROWS2 * DD;
  u16* bufH  = bufB + ROWS2 * DD;
  u16* qkv   = bufH + ROWS2 * DD;                // 3 planes
  u16* attnb = qkv + 3 * ROWS2 * DD;
  u16* wt    = attnb + ROWS2 * DD;               // 786432
  u16* w1t   = wt + 786432;                      // 32768
  float* st1 = (float*)(w1t + 32768);            // 2048*32
  float* st2 = st1 + ROWS2 * 32;
  float* acc = st2 + ROWS2 * 32;                 // 256 floats: losses, ticket, barrier lines
  int* idxb  = (int*)(acc + 256);                // 2048 ints
  float* out_f = (float*)d_out;

  head_kernel<<<832, 256, 0, stream>>>(score_s, score_t, idxb, acc,
                                       head_W1, head_W2, intra_W, cross_W, aff_A, cls_W1,
                                       wt, w1t);
  mega_kernel<<<NBLK, 256, 0, stream>>>(feat_s, feat_t, idxb, nodes, wt, w1t,
                                        head_b1, head_b2, intra_b, cross_b,
                                        cls_b1, cls_W2, cls_b2,
                                        bufA, bufB, bufH, qkv, attnb,
                                        st1, st2, acc, out_f);
}

// Round 10
// 216.770 us; speedup vs baseline: 4.0387x; 3.4970x over previous
//
#include <hip/hip_runtime.h>
#include <math.h>

#define BIMG 8
#define HW 9216
#define CENC 512
#define NN 128
#define DD 256
#define NHEAD 8
#define DH 32
#define ROWS1 1024
#define ROWS2 2048
#define TAILB 520   // 8 sinkhorn + 512 cls blocks

typedef unsigned long long ull;
typedef unsigned short u16;
typedef __attribute__((ext_vector_type(4))) float f32x4;
typedef __attribute__((ext_vector_type(4))) unsigned u32x4;
typedef __attribute__((ext_vector_type(2))) unsigned u32x2;

__device__ __forceinline__ u16 f2bf(float f) {
  unsigned u = __float_as_uint(f);
  u += 0x7fffu + ((u >> 16) & 1u);
  return (u16)(u >> 16);
}
__device__ __forceinline__ float bf2f(unsigned h) { return __uint_as_float(h << 16); }
__device__ __forceinline__ unsigned pack2(float a, float b) {
  return (unsigned)f2bf(a) | ((unsigned)f2bf(b) << 16);
}
__device__ __forceinline__ void mfma_b(f32x4& acc, u32x4 a, u32x4 b) {
  asm volatile("v_mfma_f32_16x16x32_bf16 %0, %1, %2, %0" : "+v"(acc) : "v"(a), "v"(b));
}

__device__ __forceinline__ ull cmpex_keep(ull k, ull o, bool keepMax) {
  return ((k > o) == keepMax) ? k : o;
}
__device__ __forceinline__ void bsort64(ull& k, int lane) {
#pragma unroll
  for (int size = 2; size <= 64; size <<= 1) {
#pragma unroll
    for (int stride = size >> 1; stride > 0; stride >>= 1) {
      ull o = __shfl_xor(k, stride);
      bool keepMax = (((lane & size) == 0) == ((lane & stride) == 0));
      k = cmpex_keep(k, o, keepMax);
    }
  }
}
__device__ __forceinline__ void bmerge64(ull& top, ull b, int lane) {
  ull rev = __shfl_xor(b, 63);
  ull m = top > rev ? top : rev;
#pragma unroll
  for (int stride = 32; stride > 0; stride >>= 1) {
    ull o = __shfl_xor(m, stride);
    m = cmpex_keep(m, o, (lane & stride) == 0);
  }
  top = m;
}

// ---- launch 1: 0..31 top-64 ; 32..799 weight transpose ; 800..831 cls_W1 -> bf16 ----
__global__ __launch_bounds__(256) void head_kernel(const float* __restrict__ score_s,
                                                   const float* __restrict__ score_t,
                                                   int* __restrict__ idx_out,
                                                   float* __restrict__ loss_acc,
                                                   const float* __restrict__ hw1,
                                                   const float* __restrict__ hw2,
                                                   const float* __restrict__ iw,
                                                   const float* __restrict__ cw,
                                                   const float* __restrict__ aw,
                                                   const float* __restrict__ clsW1,
                                                   u16* __restrict__ wt,
                                                   u16* __restrict__ w1t) {
  __shared__ ull sm[256];
  __shared__ float tile[32][33];
  int tid = threadIdx.x;
  if (blockIdx.x < 32) {
    int blk = blockIdx.x;
    int bi = blk >> 1, neg = blk & 1;
    int lane = tid & 63, w = tid >> 6;
    if (blk == 0 && tid < 4) loss_acc[tid] = 0.f;   // loss0, loss1, pad, ticket
    const float* sp = (bi < 8 ? score_s : score_t) + (size_t)(bi & 7) * HW;
    int q0 = w * 36;
    ull keys[36];
#pragma unroll
    for (int j = 0; j < 36; ++j) {
      float x = sp[(q0 + j) * 64 + lane];
      unsigned ub = __float_as_uint(x);
      unsigned u = (ub & 0x80000000u) ? ~ub : (ub | 0x80000000u);
      if (neg) u = ~u;
      int gi = (q0 + j) * 64 + lane;
      keys[j] = ((ull)u << 32) | (unsigned)(~gi);
    }
    ull top1 = keys[0];  bsort64(top1, lane);
    ull top2 = keys[18]; bsort64(top2, lane);
#pragma unroll
    for (int j = 1; j < 18; ++j) {
      ull k1 = keys[j], k2 = keys[18 + j];
      bsort64(k1, lane);
      bsort64(k2, lane);
      bmerge64(top1, k1, lane);
      bmerge64(top2, k2, lane);
    }
    bmerge64(top1, top2, lane);
    sm[w * 64 + lane] = top1;
    __syncthreads();
    if (w < 2) {
      ull a = sm[(2 * w) * 64 + lane];
      ull b = sm[(2 * w + 1) * 64 + (63 - lane)];
      ull m = a > b ? a : b;
#pragma unroll
      for (int stride = 32; stride > 0; stride >>= 1) {
        ull o = __shfl_xor(m, stride);
        m = cmpex_keep(m, o, (lane & stride) == 0);
      }
      sm[(2 * w) * 64 + lane] = m;
    }
    __syncthreads();
    if (w == 0) {
      ull a = sm[lane];
      ull b = sm[128 + (63 - lane)];
      ull m = a > b ? a : b;
#pragma unroll
      for (int stride = 32; stride > 0; stride >>= 1) {
        ull o = __shfl_xor(m, stride);
        m = cmpex_keep(m, o, (lane & stride) == 0);
      }
      idx_out[bi * NN + neg * 64 + lane] = (int)(~(unsigned)(m & 0xffffffffull));
    }
  } else if (blockIdx.x < 800) {
    int bid = blockIdx.x - 32;
    const float* src; u16* dst; int K, k0, n0;
    if (bid < 128) {
      src = hw1; dst = wt; K = 512;
      k0 = (bid >> 3) * 32; n0 = (bid & 7) * 32;
    } else {
      int id2 = bid - 128;
      int m = id2 >> 6, tt = id2 & 63;
      K = 256;
      k0 = (tt >> 3) * 32; n0 = (tt & 7) * 32;
      src = (m == 0) ? hw2 : (m < 5) ? iw + (size_t)(m - 1) * 65536
          : (m < 9) ? cw + (size_t)(m - 5) * 65536 : aw;
      dst = wt + 131072 + (size_t)m * 65536;
    }
    int r = tid >> 3, c = (tid & 7) * 4;
    float4 v = *(const float4*)&src[(size_t)(k0 + r) * 256 + n0 + c];
    tile[r][c] = v.x; tile[r][c + 1] = v.y; tile[r][c + 2] = v.z; tile[r][c + 3] = v.w;
    __syncthreads();
    u32x2 o;
    o[0] = pack2(tile[c][r], tile[c + 1][r]);
    o[1] = pack2(tile[c + 2][r], tile[c + 3][r]);
    *(u32x2*)&dst[(size_t)(n0 + r) * K + k0 + c] = o;
  } else {
    int bid3 = blockIdx.x - 800;     // cls_W1 [256][128] -> bf16 [128][256]
    int k0 = (bid3 >> 2) * 32, n0 = (bid3 & 3) * 32;
    int r = tid >> 3, c = (tid & 7) * 4;
    float4 v = *(const float4*)&clsW1[(size_t)(k0 + r) * 128 + n0 + c];
    tile[r][c] = v.x; tile[r][c + 1] = v.y; tile[r][c + 2] = v.z; tile[r][c + 3] = v.w;
    __syncthreads();
    u32x2 o;
    o[0] = pack2(tile[c][r], tile[c + 1][r]);
    o[1] = pack2(tile[c + 2][r], tile[c + 3][r]);
    *(u32x2*)&w1t[(size_t)(n0 + r) * 256 + k0 + c] = o;
  }
}

// ---- launch 2: fused gather + GEMM1 (16x256 tile, K=512), writes bufA + st1 ----
// 128 blocks x 256 threads; each block gathers its own 16 A-rows into LDS.
__global__ __launch_bounds__(256) void gemm1_fused(const float* __restrict__ feat_s,
                                                   const float* __restrict__ feat_t,
                                                   const int* __restrict__ idxb,
                                                   const u16* __restrict__ wt_h1,
                                                   const float* __restrict__ head_b1,
                                                   u16* __restrict__ bufA,
                                                   float* __restrict__ st1) {
  __shared__ u16 As[16][520];
  __shared__ u16 Bs[256][40];
  int t = threadIdx.x, l = t & 63, cg = t >> 6;
  int m0 = blockIdx.x * 16;
  // gather: row r, channels 2t and 2t+1 (scattered, stride HW)
#pragma unroll
  for (int row = 0; row < 16; ++row) {
    int grow = m0 + row;
    int bi = grow >> 7, n = grow & 127, b = bi & 7;
    const float* fp = (bi < 8) ? feat_s : feat_t;
    int pos = idxb[bi * NN + n];
    const float* src = fp + (size_t)b * CENC * HW + pos;
    float f0 = src[(size_t)(2 * t) * HW];
    float f1 = src[(size_t)(2 * t + 1) * HW];
    *(unsigned*)&As[row][2 * t] = pack2(f0, f1);
  }
  __syncthreads();
  f32x4 acc[4];
#pragma unroll
  for (int i = 0; i < 4; ++i) acc[i] = (f32x4){0.f, 0.f, 0.f, 0.f};
  for (int kc = 0; kc < 16; ++kc) {
#pragma unroll
    for (int i = 0; i < 4; ++i) {
      int e = t + i * 256;
      int nn2 = e >> 2, ch8 = (e & 3) * 8;
      *(u32x4*)&Bs[nn2][ch8] = *(const u32x4*)&wt_h1[(size_t)nn2 * 512 + kc * 32 + ch8];
    }
    __syncthreads();
    u32x4 af = *(const u32x4*)&As[l & 15][kc * 32 + (l >> 4) * 8];
#pragma unroll
    for (int i = 0; i < 4; ++i) {
      u32x4 bf = *(const u32x4*)&Bs[cg * 64 + i * 16 + (l & 15)][(l >> 4) * 8];
      mfma_b(acc[i], af, bf);
    }
    __syncthreads();
  }
  asm volatile("s_nop 7\n\ts_nop 7" ::);
  int rbase = m0 + (l >> 4) * 4;
#pragma unroll
  for (int i = 0; i < 4; ++i) {
    int col = cg * 64 + i * 16 + (l & 15);
    float bb = head_b1[col];
#pragma unroll
    for (int r = 0; r < 4; ++r) {
      int row = rbase + r;
      float o = acc[i][r] + bb;
      bufA[(size_t)row * 256 + col] = f2bf(o);
      float s = o, q = o * o;
#pragma unroll
      for (int m = 1; m < 16; m <<= 1) { s += __shfl_xor(s, m); q += __shfl_xor(q, m); }
      if ((l & 15) == 0) {
        st1[(size_t)row * 32 + cg * 4 + i]      = s;
        st1[(size_t)row * 32 + 16 + cg * 4 + i] = q;
      }
    }
  }
}

// ---------------- bf16 MFMA GEMM, full-K LDS stage, barrier-free K loop ----------------
// stats: 32 floats/row = 16 col-block sums (16-col granularity) + 16 sumsqs
template<int K>
__global__ __launch_bounds__(256) void gemm_mf(const u16* __restrict__ A,
                                               const u16* __restrict__ Wt,
                                               const float* __restrict__ bias,
                                               u16* __restrict__ Cb,
                                               float* __restrict__ Cf,
                                               int ldc, int f32rows,
                                               const float* __restrict__ in_stats, int in_relu,
                                               float* __restrict__ out_stats,
                                               int Az, int Wz, int Cbz, int Cfz, int bz) {
  constexpr int LDK = K + 8;
  constexpr int KC = K / 8;
  __shared__ u16 As[32][LDK];
  __shared__ u16 Bs[64][LDK];
  __shared__ float mS[32], rS[32];
  int z = blockIdx.z;
  A  += (size_t)z * Az;
  Wt += (size_t)z * Wz;
  if (Cb)   Cb += (size_t)z * Cbz;
  if (Cf)   Cf += (size_t)z * Cfz;
  if (bias) bias += (size_t)z * bz;
  int n0 = blockIdx.x * 64, m0 = blockIdx.y * 32;
  int t = threadIdx.x;
  if (in_stats) {
    if (t < 32) {
      const float* sp = in_stats + (size_t)(m0 + t) * 32;
      float s = 0.f, q = 0.f;
#pragma unroll
      for (int i = 0; i < 16; ++i) { s += sp[i]; q += sp[16 + i]; }
      float mm = s * (1.f / 256.f);
      float var = q * (1.f / 256.f) - mm * mm;
      mS[t] = mm;
      rS[t] = rsqrtf(fmaxf(var, 0.f) + 1e-5f);
    }
    __syncthreads();
  }
  for (int i = t; i < 32 * KC; i += 256) {
    int row = i / KC, c8 = (i % KC) * 8;
    u32x4 av = *(const u32x4*)&A[(size_t)(m0 + row) * K + c8];
    if (in_stats) {
      float mm = mS[row], rr = rS[row];
#pragma unroll
      for (int j = 0; j < 4; ++j) {
        float f0 = (bf2f(av[j] & 0xffffu) - mm) * rr;
        float f1 = (bf2f(av[j] >> 16) - mm) * rr;
        if (in_relu) { f0 = fmaxf(f0, 0.f); f1 = fmaxf(f1, 0.f); }
        av[j] = pack2(f0, f1);
      }
    }
    *(u32x4*)&As[row][c8] = av;
  }
  for (int i = t; i < 64 * KC; i += 256) {
    int row = i / KC, c8 = (i % KC) * 8;
    *(u32x4*)&Bs[row][c8] = *(const u32x4*)&Wt[(size_t)(n0 + row) * K + c8];
  }
  __syncthreads();
  int l = t & 63, w = t >> 6;
  int wr = w >> 1, wc = w & 1;
  int fra = wr * 16 + (l & 15);
  int frk = (l >> 4) * 8;
  int fb0 = wc * 32 + (l & 15), fb1 = fb0 + 16;
  f32x4 acc0 = {0.f, 0.f, 0.f, 0.f};
  f32x4 acc1 = {0.f, 0.f, 0.f, 0.f};
#pragma unroll
  for (int ks = 0; ks < K / 32; ++ks) {
    u32x4 af = *(const u32x4*)&As[fra][ks * 32 + frk];
    u32x4 b0 = *(const u32x4*)&Bs[fb0][ks * 32 + frk];
    u32x4 b1 = *(const u32x4*)&Bs[fb1][ks * 32 + frk];
    mfma_b(acc0, af, b0);
    mfma_b(acc1, af, b1);
  }
  asm volatile("s_nop 7\n\ts_nop 7" ::);
  int col0 = n0 + wc * 32 + (l & 15);
  int rbase = m0 + wr * 16 + (l >> 4) * 4;
  float b0 = 0.f, b1 = 0.f;
  if (bias) { b0 = bias[col0]; b1 = bias[col0 + 16]; }
#pragma unroll
  for (int r = 0; r < 4; ++r) {
    int row = rbase + r;
    float o0 = acc0[r] + b0;
    float o1 = acc1[r] + b1;
    if (Cb) {
      Cb[(size_t)row * 256 + col0]      = f2bf(o0);
      Cb[(size_t)row * 256 + col0 + 16] = f2bf(o1);
    }
    if (Cf && row < ROWS1) {
      Cf[(size_t)row * ldc + col0]      = o0;
      Cf[(size_t)row * ldc + col0 + 16] = o1;
    }
    if (out_stats) {
      float s0 = o0, q0 = o0 * o0, s1 = o1, q1 = o1 * o1;
#pragma unroll
      for (int m = 1; m < 16; m <<= 1) {
        s0 += __shfl_xor(s0, m); q0 += __shfl_xor(q0, m);
        s1 += __shfl_xor(s1, m); q1 += __shfl_xor(q1, m);
      }
      if ((l & 15) == 0) {
        int base = (n0 >> 4) + wc * 2;
        out_stats[(size_t)row * 32 + base]          = s0;
        out_stats[(size_t)row * 32 + base + 1]      = s1;
        out_stats[(size_t)row * 32 + 16 + base]     = q0;
        out_stats[(size_t)row * 32 + 16 + base + 1] = q1;
      }
    }
  }
}

// ---------------- attention: block = (bb, h, qh) -> 64 q-rows, wave p owns j-quarter ----------------
__global__ __launch_bounds__(256) void attn_kernel(const u16* __restrict__ q,
                                                   const u16* __restrict__ k,
                                                   const u16* __restrict__ v,
                                                   u16* __restrict__ o, int swap) {
  __shared__ __align__(16) float Ks[NN][DH];
  __shared__ __align__(16) float Vs[NN][DH];
  __shared__ __align__(16) float Ex[64][3][34];
  int blk = blockIdx.x;
  int bb = blk >> 4, h = (blk >> 1) & 7, qh = blk & 1;
  int kb = swap ? (bb ^ 8) : bb;
  int t = threadIdx.x;
  int rr = t & 63, part = t >> 6;
  for (int e = t; e < 1024; e += 256) {
    int which = e >> 9;
    int idx2 = e & 511;
    int r = idx2 >> 2, c8 = (idx2 & 3) * 8;
    u32x4 val = *(const u32x4*)&(which ? v : k)[(size_t)(kb * NN + r) * DD + h * DH + c8];
    float* dst = which ? &Vs[r][c8] : &Ks[r][c8];
#pragma unroll
    for (int i = 0; i < 4; ++i) {
      dst[2 * i]     = bf2f(val[i] & 0xffffu);
      dst[2 * i + 1] = bf2f(val[i] >> 16);
    }
  }
  __syncthreads();
  int qrow = bb * NN + qh * 64 + rr;
  float4 q4[8];
  {
    const u16* qp = q + (size_t)qrow * DD + h * DH;
#pragma unroll
    for (int c4 = 0; c4 < 4; ++c4) {
      u32x4 u = *(const u32x4*)&qp[c4 * 8];
      q4[c4 * 2].x = bf2f(u[0] & 0xffffu); q4[c4 * 2].y = bf2f(u[0] >> 16);
      q4[c4 * 2].z = bf2f(u[1] & 0xffffu); q4[c4 * 2].w = bf2f(u[1] >> 16);
      q4[c4 * 2 + 1].x = bf2f(u[2] & 0xffffu); q4[c4 * 2 + 1].y = bf2f(u[2] >> 16);
      q4[c4 * 2 + 1].z = bf2f(u[3] & 0xffffu); q4[c4 * 2 + 1].w = bf2f(u[3] >> 16);
    }
  }
  const float scale = 0.17677669529663687f;
  int j0 = part * 32;
  float mx = -1e30f;
  for (int j = j0; j < j0 + 32; ++j) {
    const float4* kp = (const float4*)Ks[j];
    float s = 0.f;
#pragma unroll
    for (int c4 = 0; c4 < 8; ++c4) {
      float4 kv = kp[c4];
      s += q4[c4].x * kv.x + q4[c4].y * kv.y + q4[c4].z * kv.z + q4[c4].w * kv.w;
    }
    mx = fmaxf(mx, s * scale);
  }
  float acc[DH];
#pragma unroll
  for (int c = 0; c < DH; ++c) acc[c] = 0.f;
  float den = 0.f;
  for (int j = j0; j < j0 + 32; ++j) {
    const float4* kp = (const float4*)Ks[j];
    float s = 0.f;
#pragma unroll
    for (int c4 = 0; c4 < 8; ++c4) {
      float4 kv = kp[c4];
      s += q4[c4].x * kv.x + q4[c4].y * kv.y + q4[c4].z * kv.z + q4[c4].w * kv.w;
    }
    float e = __expf(s * scale - mx);
    den += e;
    const float4* vp = (const float4*)Vs[j];
#pragma unroll
    for (int c4 = 0; c4 < 8; ++c4) {
      float4 vv = vp[c4];
      acc[c4 * 4 + 0] += e * vv.x; acc[c4 * 4 + 1] += e * vv.y;
      acc[c4 * 4 + 2] += e * vv.z; acc[c4 * 4 + 3] += e * vv.w;
    }
  }
  if (part) {
#pragma unroll
    for (int c = 0; c < DH; ++c) Ex[rr][part - 1][c] = acc[c];
    Ex[rr][part - 1][32] = mx;
    Ex[rr][part - 1][33] = den;
  }
  __syncthreads();
  if (part == 0) {
    float M = mx;
#pragma unroll
    for (int p = 0; p < 3; ++p) M = fmaxf(M, Ex[rr][p][32]);
    float f0 = __expf(mx - M);
    float fp[3];
    float dt = den * f0;
#pragma unroll
    for (int p = 0; p < 3; ++p) { fp[p] = __expf(Ex[rr][p][32] - M); dt += Ex[rr][p][33] * fp[p]; }
    float inv = 1.0f / dt;
    unsigned ovu[16];
#pragma unroll
    for (int c = 0; c < 16; ++c) {
      float x0 = acc[2 * c] * f0, x1 = acc[2 * c + 1] * f0;
#pragma unroll
      for (int p = 0; p < 3; ++p) { x0 += Ex[rr][p][2 * c] * fp[p]; x1 += Ex[rr][p][2 * c + 1] * fp[p]; }
      ovu[c] = pack2(x0 * inv, x1 * inv);
    }
    unsigned* op = (unsigned*)(o + (size_t)qrow * DD + h * DH);
#pragma unroll
    for (int i = 0; i < 4; ++i) {
      u32x4 w4;
      w4[0] = ovu[4 * i]; w4[1] = ovu[4 * i + 1]; w4[2] = ovu[4 * i + 2]; w4[3] = ovu[4 * i + 3];
      *(u32x4*)&op[4 * i] = w4;
    }
  }
}

// ---------------- tail: 0..7 = aff+NT+sinkhorn+focal ; 8..519 = cls (4 rows each) ----------------
struct SkSmem {
  union { u16 tmpL[128][264]; float Km[128][133]; } u;
  float u_[NN];
  float v_[NN];
  float red[20];
};
struct ClsSmem {
  float xs[4][256];
  float part[4][128];
  float red[8];
};
union TailSmem { SkSmem sk; ClsSmem cls; };

__device__ __forceinline__ void ticket_finalize(float* acc, float* out) {
  __threadfence();
  int tk = atomicAdd((int*)acc + 3, 1);
  if (tk == TAILB - 1) {
    float a0 = atomicAdd(acc + 0, 0.0f);
    float a1 = atomicAdd(acc + 1, 0.0f);
    out[ROWS1 * DD] = a0 + 10.0f * a1;
  }
}

__global__ __launch_bounds__(1024) void tail_kernel(const u16* __restrict__ bufH,
                                                    const u16* __restrict__ wt_af,
                                                    const u16* __restrict__ w1t,
                                                    const float* __restrict__ b1,
                                                    const float* __restrict__ W2,
                                                    const float* __restrict__ b2,
                                                    float* __restrict__ acc,
                                                    float* __restrict__ out) {
  __shared__ TailSmem sm;
  int t = threadIdx.x;
  int bid = blockIdx.x;
  if (bid < 8) {
    int b = bid;
    int l = t & 63, w = t >> 6;
    int tr = w >> 1;
    const u16* c1 = bufH + (size_t)(b * 128) * 256;
    const u16* c2 = bufH + (size_t)(1024 + b * 128) * 256;
    {
      int tcB = (w & 1) * 8;
      f32x4 accA[8];
#pragma unroll
      for (int i = 0; i < 8; ++i) accA[i] = (f32x4){0.f, 0.f, 0.f, 0.f};
      for (int ks = 0; ks < 8; ++ks) {
        int kk = ks * 32 + (l >> 4) * 8;
        u32x4 af = *(const u32x4*)&c1[(size_t)(tr * 16 + (l & 15)) * 256 + kk];
#pragma unroll
        for (int i = 0; i < 8; ++i) {
          u32x4 bf = *(const u32x4*)&wt_af[(size_t)((tcB + i) * 16 + (l & 15)) * 256 + kk];
          mfma_b(accA[i], af, bf);
        }
      }
      asm volatile("s_nop 7\n\ts_nop 7" ::);
      int rb = tr * 16 + (l >> 4) * 4;
#pragma unroll
      for (int i = 0; i < 8; ++i) {
        int col = (tcB + i) * 16 + (l & 15);
#pragma unroll
        for (int r2 = 0; r2 < 4; ++r2)
          sm.sk.u.tmpL[rb + r2][col] = f2bf(accA[i][r2]);
      }
    }
    __syncthreads();
    f32x4 aB[4];
    {
      int tcB = (w & 1) * 4;
#pragma unroll
      for (int i = 0; i < 4; ++i) aB[i] = (f32x4){0.f, 0.f, 0.f, 0.f};
      for (int ks = 0; ks < 8; ++ks) {
        int kk = ks * 32 + (l >> 4) * 8;
        u32x4 af = *(const u32x4*)&sm.sk.u.tmpL[tr * 16 + (l & 15)][kk];
#pragma unroll
        for (int i = 0; i < 4; ++i) {
          u32x4 bf = *(const u32x4*)&c2[(size_t)((tcB + i) * 16 + (l & 15)) * 256 + kk];
          mfma_b(aB[i], af, bf);
        }
      }
      asm volatile("s_nop 7\n\ts_nop 7" ::);
    }
    __syncthreads();   // all tmpL reads complete before aliased Km writes
    {
      int tcB = (w & 1) * 4;
      int rb = tr * 16 + (l >> 4) * 4;
#pragma unroll
      for (int i = 0; i < 4; ++i) {
        int col = (tcB + i) * 16 + (l & 15);
#pragma unroll
        for (int r2 = 0; r2 < 4; ++r2)
          sm.sk.u.Km[rb + r2][col] = aB[i][r2];
      }
    }
    __syncthreads();
    int r = t >> 3, cg = t & 7;
    int c = t >> 3, rg = t & 7;
    float kr[16], kc[16];
    {
#pragma unroll
      for (int q4 = 0; q4 < 4; ++q4) {
        float4 f = *(const float4*)&sm.sk.u.Km[r][cg * 16 + q4 * 4];
        kr[q4 * 4 + 0] = f.x; kr[q4 * 4 + 1] = f.y; kr[q4 * 4 + 2] = f.z; kr[q4 * 4 + 3] = f.w;
      }
#pragma unroll
      for (int q = 0; q < 16; ++q)
        kc[q] = sm.sk.u.Km[rg * 16 + q][c];
    }
    float s = 0.f;
#pragma unroll
    for (int q = 0; q < 16; ++q) s += kr[q];
    for (int m = 1; m < 64; m <<= 1) s += __shfl_xor(s, m);
    if ((t & 63) == 0) sm.sk.red[t >> 6] = s;
    __syncthreads();
    if (t == 0) { float tt = 0.f; for (int i = 0; i < 16; ++i) tt += sm.sk.red[i]; sm.sk.red[16] = tt; }
    __syncthreads();
    float mu = sm.sk.red[16] * (1.0f / 16384.f);
    __syncthreads();
    float sq = 0.f;
#pragma unroll
    for (int q = 0; q < 16; ++q) { float d = kr[q] - mu; sq += d * d; }
    for (int m = 1; m < 64; m <<= 1) sq += __shfl_xor(sq, m);
    if ((t & 63) == 0) sm.sk.red[t >> 6] = sq;
    __syncthreads();
    if (t == 0) { float tt = 0.f; for (int i = 0; i < 16; ++i) tt += sm.sk.red[i]; sm.sk.red[17] = tt; }
    __syncthreads();
    float inv = 1.0f / sqrtf(sm.sk.red[17] * (1.0f / 16384.f) + 1e-5f);
#pragma unroll
    for (int q = 0; q < 16; ++q) { kr[q] = (kr[q] - mu) * inv; kc[q] = (kc[q] - mu) * inv; }
    if (t < NN) { sm.sk.u_[t] = 0.f; sm.sk.v_[t] = 0.f; }
    __syncthreads();
    for (int iter = 0; iter < 10; ++iter) {
      float tmp[16];
      {
        const float4* vp = (const float4*)(sm.sk.v_ + cg * 16);
#pragma unroll
        for (int q4 = 0; q4 < 4; ++q4) {
          float4 f = vp[q4];
          tmp[q4 * 4 + 0] = kr[q4 * 4 + 0] - f.x; tmp[q4 * 4 + 1] = kr[q4 * 4 + 1] - f.y;
          tmp[q4 * 4 + 2] = kr[q4 * 4 + 2] - f.z; tmp[q4 * 4 + 3] = kr[q4 * 4 + 3] - f.w;
        }
        float mx = tmp[0];
#pragma unroll
        for (int q = 1; q < 16; ++q) mx = fmaxf(mx, tmp[q]);
        for (int m = 1; m < 8; m <<= 1) mx = fmaxf(mx, __shfl_xor(mx, m));
        float smv = 0.f;
#pragma unroll
        for (int q = 0; q < 16; ++q) smv += __expf(tmp[q] - mx);
        for (int m = 1; m < 8; m <<= 1) smv += __shfl_xor(smv, m);
        if (cg == 0) sm.sk.u_[r] = mx + __logf(smv);
      }
      __syncthreads();
      {
        const float4* up = (const float4*)(sm.sk.u_ + rg * 16);
#pragma unroll
        for (int q4 = 0; q4 < 4; ++q4) {
          float4 f = up[q4];
          tmp[q4 * 4 + 0] = kc[q4 * 4 + 0] - f.x; tmp[q4 * 4 + 1] = kc[q4 * 4 + 1] - f.y;
          tmp[q4 * 4 + 2] = kc[q4 * 4 + 2] - f.z; tmp[q4 * 4 + 3] = kc[q4 * 4 + 3] - f.w;
        }
        float mx = tmp[0];
#pragma unroll
        for (int q = 1; q < 16; ++q) mx = fmaxf(mx, tmp[q]);
        for (int m = 1; m < 8; m <<= 1) mx = fmaxf(mx, __shfl_xor(mx, m));
        float smv = 0.f;
#pragma unroll
        for (int q = 0; q < 16; ++q) smv += __expf(tmp[q] - mx);
        for (int m = 1; m < 8; m <<= 1) smv += __shfl_xor(smv, m);
        if (rg == 0) sm.sk.v_[c] = mx + __logf(smv);
      }
      __syncthreads();
    }
    float ur = sm.sk.u_[r];
    float fsum = 0.f;
    {
      const float4* vp = (const float4*)(sm.sk.v_ + cg * 16);
#pragma unroll
      for (int q4 = 0; q4 < 4; ++q4) {
        float4 f = vp[q4];
        float vv[4] = {f.x, f.y, f.z, f.w};
#pragma unroll
        for (int j = 0; j < 4; ++j) {
          float P = __expf(kr[q4 * 4 + j] - ur - vv[j]);
          float pt = fminf(fmaxf(P, 1e-6f), 1.0f - 1e-6f);
          int col = cg * 16 + q4 * 4 + j;
          bool gt = (r < 64) == (col < 64);
          float wgt = gt ? (-0.25f * (1.f - pt) * (1.f - pt)) : (-0.75f * pt * pt);
          float lg = gt ? __logf(pt) : __logf(1.f - pt);
          fsum += wgt * lg;
        }
      }
    }
    for (int m = 1; m < 64; m <<= 1) fsum += __shfl_xor(fsum, m);
    if ((t & 63) == 0) sm.sk.red[t >> 6] = fsum;
    __syncthreads();
    if (t == 0) {
      float tt = 0.f; for (int i = 0; i < 16; ++i) tt += sm.sk.red[i];
      atomicAdd(acc + 1, tt * (1.0f / 131072.f));
      ticket_finalize(acc, out);
    }
  } else {
    int row0 = (bid - 8) * 4;
    {
      int rr = t >> 8, cc = t & 255;
      sm.cls.xs[rr][cc] = bf2f(bufH[(size_t)(row0 + rr) * 256 + cc]);
    }
    __syncthreads();
    int grp = t >> 8, col = t & 127, kh = (t >> 7) & 1;
    const u16* wp = w1t + (size_t)col * 256 + kh * 128;
    const float* xp = &sm.cls.xs[grp][kh * 128];
    float h = 0.f;
#pragma unroll
    for (int i = 0; i < 16; ++i) {
      u32x4 wv = *(const u32x4*)&wp[i * 8];
      const float* x8 = xp + i * 8;
      h += x8[0] * bf2f(wv[0] & 0xffffu) + x8[1] * bf2f(wv[0] >> 16)
         + x8[2] * bf2f(wv[1] & 0xffffu) + x8[3] * bf2f(wv[1] >> 16)
         + x8[4] * bf2f(wv[2] & 0xffffu) + x8[5] * bf2f(wv[2] >> 16)
         + x8[6] * bf2f(wv[3] & 0xffffu) + x8[7] * bf2f(wv[3] >> 16);
    }
    if (kh == 1) sm.cls.part[grp][col] = h;
    __syncthreads();
    if (kh == 0) {
      float z = h + sm.cls.part[grp][col] + b1[col];
      float p = fmaxf(z, 0.f) * W2[col];
#pragma unroll
      for (int m = 1; m < 64; m <<= 1) p += __shfl_xor(p, m);
      if ((t & 63) == 0) sm.cls.red[grp * 2 + ((t >> 6) & 1)] = p;
    }
    __syncthreads();
    if (t == 0) {
      float total = 0.f;
      float bb2 = b2[0];
#pragma unroll
      for (int g = 0; g < 4; ++g) {
        float z = sm.cls.red[2 * g] + sm.cls.red[2 * g + 1] + bb2;
        float lab = (((row0 + g) & 127) < 64) ? 1.f : 0.f;
        total += fmaxf(z, 0.f) - z * lab + log1pf(__expf(-fabsf(z)));
      }
      atomicAdd(acc, total * (1.0f / 1024.0f));
      ticket_finalize(acc, out);
    }
  }
}

extern "C" void kernel_launch(void* const* d_in, const int* in_sizes, int n_in,
                              void* d_out, int out_size, void* d_ws, size_t ws_size,
                              hipStream_t stream) {
  const float* feat_s  = (const float*)d_in[0];
  const float* score_s = (const float*)d_in[1];
  const float* feat_t  = (const float*)d_in[2];
  const float* score_t = (const float*)d_in[3];
  const float* head_W1 = (const float*)d_in[4];
  const float* head_b1 = (const float*)d_in[5];
  const float* head_W2 = (const float*)d_in[6];
  const float* head_b2 = (const float*)d_in[7];
  const float* intra_W = (const float*)d_in[8];
  const float* intra_b = (const float*)d_in[9];
  const float* cross_W = (const float*)d_in[10];
  const float* cross_b = (const float*)d_in[11];
  const float* cls_W1  = (const float*)d_in[12];
  const float* cls_b1  = (const float*)d_in[13];
  const float* cls_W2  = (const float*)d_in[14];
  const float* cls_b2  = (const float*)d_in[15];
  const float* aff_A   = (const float*)d_in[16];

  u16* bufA  = (u16*)d_ws;                       // 2048*256
  u16* bufB  = bufA + ROWS2 * DD;
  u16* bufH  = bufB + ROWS2 * DD;
  u16* qkv   = bufH + ROWS2 * DD;                // 3 planes
  u16* attnb = qkv + 3 * ROWS2 * DD;
  u16* wt    = attnb + ROWS2 * DD;               // 786432
  u16* w1t   = wt + 786432;                      // 32768
  float* st1 = (float*)(w1t + 32768);            // 2048*32
  float* st2 = st1 + ROWS2 * 32;
  float* acc = st2 + ROWS2 * 32;                 // loss0, loss1, pad, ticket
  int* idxb  = (int*)(acc + 8);                  // 2048 ints
  float* out_f = (float*)d_out;

  u16* wt_h1 = wt;
  u16* wt_h2 = wt + 131072;
  u16* wt_in = wt_h2 + 65536;
  u16* wt_cr = wt_in + 4 * 65536;
  u16* wt_af = wt_cr + 4 * 65536;

  head_kernel<<<832, 256, 0, stream>>>(score_s, score_t, idxb, acc,
                                       head_W1, head_W2, intra_W, cross_W, aff_A, cls_W1,
                                       wt, w1t);
  // fused gather + GEMM1 (K=512) -> bufA, st1
  gemm1_fused<<<128, 256, 0, stream>>>(feat_s, feat_t, idxb, wt_h1, head_b1, bufA, st1);

  dim3 g1(4, 64, 1);
  dim3 gq(4, 64, 3);
  const float* nulf = nullptr;
  float* nulw = nullptr;

  gemm_mf<256><<<g1, 256, 0, stream>>>(bufA, wt_h2, head_b2, bufB, nulw,
                                       0, 0, st1, 1, st2, 0, 0, 0, 0, 0);
  gemm_mf<256><<<gq, 256, 0, stream>>>(bufB, wt_in, intra_b, qkv, nulw,
                                       0, 0, st2, 0, nulw, 0, 65536, ROWS2 * DD, 0, 256);
  attn_kernel<<<256, 256, 0, stream>>>(qkv, qkv + ROWS2 * DD, qkv + 2 * ROWS2 * DD,
                                       attnb, 0);
  gemm_mf<256><<<g1, 256, 0, stream>>>(attnb, wt_in + 3 * 65536, intra_b + 768, bufH, nulw,
                                       0, 0, nulf, 0, nulw, 0, 0, 0, 0, 0);   // G
  gemm_mf<256><<<gq, 256, 0, stream>>>(bufH, wt_cr, cross_b, qkv, nulw,
                                       0, 0, nulf, 0, nulw, 0, 65536, ROWS2 * DD, 0, 256);
  attn_kernel<<<256, 256, 0, stream>>>(qkv, qkv + ROWS2 * DD, qkv + 2 * ROWS2 * DD,
                                       attnb, 1);
  gemm_mf<256><<<g1, 256, 0, stream>>>(attnb, wt_cr + 3 * 65536, cross_b + 768, bufH, out_f,
                                       256, 0, nulf, 0, nulw, 0, 0, 0, 0, 0); // C (+n1)
  tail_kernel<<<TAILB, 1024, 0, stream>>>(bufH, wt_af, w1t, cls_b1, cls_W2, cls_b2,
                                          acc, out_f);
}